// Round 2
// baseline (298.913 us; speedup 1.0000x reference)
//
#include <hip/hip_runtime.h>

#define NRAYS 32768
#define HID   128
#define THRS  5e-5f
#define NITER 6
#define NFIX  3

__device__ __forceinline__ float softplus_f(float x) {
    // jax.nn.softplus = logaddexp(x, 0) = max(x,0) + log1p(exp(-|x|))
    return fmaxf(x, 0.0f) + log1pf(expf(-fabsf(x)));
}

// One full SDF MLP eval for this lane's point. All weight reads are
// wave-uniform (indices depend only on loop counters), so the compiler
// selects scalar (SMEM) loads -> weights live in SGPRs, FMAs are
// v_fma_f32 with one SGPR operand. No LDS anywhere.
__device__ float sdf_eval(float px, float py, float pz,
                          const float* __restrict__ W1,
                          const float* __restrict__ b1,
                          const float* __restrict__ W2,
                          const float* __restrict__ b2,
                          const float* __restrict__ W3,
                          float b3v)
{
    float acc[HID];
#pragma unroll
    for (int k = 0; k < HID; ++k) acc[k] = b2[k];

    // layer 1 + layer 2 fused: j-outer, acc[k] += softplus(l1_j) * W2[j][k]
    for (int j = 0; j < HID; ++j) {
        float t = fmaf(px, W1[j],
                  fmaf(py, W1[HID + j],
                  fmaf(pz, W1[2 * HID + j], b1[j])));
        float h = softplus_f(t);
        const float4* row = reinterpret_cast<const float4*>(W2 + j * HID);
#pragma unroll
        for (int kk = 0; kk < HID / 4; ++kk) {
            float4 w = row[kk];   // uniform address -> s_load, SGPR operand
            acc[4 * kk + 0] = fmaf(h, w.x, acc[4 * kk + 0]);
            acc[4 * kk + 1] = fmaf(h, w.y, acc[4 * kk + 1]);
            acc[4 * kk + 2] = fmaf(h, w.z, acc[4 * kk + 2]);
            acc[4 * kk + 3] = fmaf(h, w.w, acc[4 * kk + 3]);
        }
    }

    // layer 3
    float s0 = 0.f, s1 = 0.f, s2 = 0.f, s3 = 0.f;
#pragma unroll
    for (int k = 0; k < HID; k += 4) {
        s0 = fmaf(softplus_f(acc[k + 0]), W3[k + 0], s0);
        s1 = fmaf(softplus_f(acc[k + 1]), W3[k + 1], s1);
        s2 = fmaf(softplus_f(acc[k + 2]), W3[k + 2], s2);
        s3 = fmaf(softplus_f(acc[k + 3]), W3[k + 3], s3);
    }
    return (s0 + s1) + (s2 + s3) + b3v;
}

__global__ __launch_bounds__(256, 1)
void sphere_trace_kernel(const float* __restrict__ rays_d,
                         const float* __restrict__ rays_o,
                         const float* __restrict__ W1, const float* __restrict__ b1,
                         const float* __restrict__ W2, const float* __restrict__ b2,
                         const float* __restrict__ W3, const float* __restrict__ b3,
                         float* __restrict__ out)
{
    const int tid = threadIdx.x;
    const int t   = blockIdx.x * 256 + tid;  // ray-channel index
    const int ray = t >> 1;
    const int ch  = t & 1;
    const float sign = ch ? -1.0f : 1.0f;

    const float b3v = b3[0];

    const float dx = rays_d[ray * 3 + 0];
    const float dy = rays_d[ray * 3 + 1];
    const float dz = rays_d[ray * 3 + 2];
    const float ox = rays_o[ray * 3 + 0];
    const float oy = rays_o[ray * 3 + 1];
    const float oz = rays_o[ray * 3 + 2];

    float z = 0.0f;
    bool mask = true;

    // initial eval at z=0 (points = origins)
    float next_sdf = sdf_eval(ox, oy, oz, W1, b1, W2, b2, W3, b3v);

    for (int it = 0; it < NITER; ++it) {
        float sv = mask ? next_sdf : 0.0f;
        sv = (sv <= THRS) ? 0.0f : sv;
        mask = mask && (sv > THRS);
        z = fmaf(sign, sv, z);

        float px = fmaf(z, dx, ox);
        float py = fmaf(z, dy, oy);
        float pz = fmaf(z, dz, oz);

        float ns = 0.0f;
        if (__ballot(mask) != 0ULL) {          // wave-level skip
            ns = sdf_eval(px, py, pz, W1, b1, W2, b2, W3, b3v);
        }
        next_sdf = mask ? ns : 0.0f;

        bool fmask = next_sdf < 0.0f;
        float step = 0.5f;
        for (int fi = 0; fi < NFIX; ++fi) {
            if (__ballot(fmask) != 0ULL) {     // wave-level skip
                float zf = fmaf(-step * sign, sv, z);
                z = fmask ? zf : z;
                px = fmaf(z, dx, ox);
                py = fmaf(z, dy, oy);
                pz = fmaf(z, dz, oz);
                float ns2 = sdf_eval(px, py, pz, W1, b1, W2, b2, W3, b3v);
                next_sdf = fmask ? ns2 : next_sdf;
                fmask = next_sdf < 0.0f;
            }
            step *= 0.5f;
        }

        // cross-channel coupling: mask &= (z[ch0] < z[ch1]) per ray
        float zo = __shfl_xor(z, 1);
        bool cond = ch ? (zo < z) : (z < zo);
        mask = mask && cond;
    }

    // final top-of-loop mask update
    float sv = mask ? next_sdf : 0.0f;
    sv = (sv <= THRS) ? 0.0f : sv;
    mask = mask && (sv > THRS);

    const float px = fmaf(z, dx, ox);
    const float py = fmaf(z, dy, oy);
    const float pz = fmaf(z, dz, oz);

    // outputs: points (2,N,3), z (2,N), mask (2,N) concatenated flat
    const size_t pbase = (size_t)ch * NRAYS * 3 + (size_t)ray * 3;
    out[pbase + 0] = px;
    out[pbase + 1] = py;
    out[pbase + 2] = pz;
    out[2 * NRAYS * 3 + (size_t)ch * NRAYS + ray] = z;
    out[2 * NRAYS * 3 + 2 * NRAYS + (size_t)ch * NRAYS + ray] = mask ? 1.0f : 0.0f;
}

extern "C" void kernel_launch(void* const* d_in, const int* in_sizes, int n_in,
                              void* d_out, int out_size, void* d_ws, size_t ws_size,
                              hipStream_t stream) {
    const float* rays_d = (const float*)d_in[0];
    const float* rays_o = (const float*)d_in[1];
    const float* W1 = (const float*)d_in[2];
    const float* b1 = (const float*)d_in[3];
    const float* W2 = (const float*)d_in[4];
    const float* b2 = (const float*)d_in[5];
    const float* W3 = (const float*)d_in[6];
    const float* b3 = (const float*)d_in[7];
    float* out = (float*)d_out;

    const int total = NRAYS * 2;              // 65536 ray-channels
    const int block = 256;
    const int grid = total / block;           // 256 blocks -> 1 per CU

    sphere_trace_kernel<<<grid, block, 0, stream>>>(
        rays_d, rays_o, W1, b1, W2, b2, W3, b3, out);
}

// Round 3
// 281.557 us; speedup vs baseline: 1.0616x; 1.0616x over previous
//
#include <hip/hip_runtime.h>

#define NRAYS 32768
#define HID   128
#define THRS  5e-5f
#define NITER 6
#define NFIX  3

__device__ __forceinline__ float softplus_f(float x) {
    // jax.nn.softplus = max(x,0) + log1p(exp(-|x|))
    return fmaxf(x, 0.0f) + log1pf(expf(-fabsf(x)));
}

struct Shared {
    const float4* T1;   // [128] packed (W1x, W1y, W1z, b1) per hidden j
    const float4* W2v;  // [128*32] swizzled: row j, chunk c=(s*8+u) at pos j*32 + 4u + s
    const float*  B2;   // [128]
    const float*  W3;   // [128]
    float b3;
};

// SDF eval for TWO points (the ray's two channels), k-slice s (0..3).
// Each lane accumulates 32 of the 128 hidden-2 units; the 4 slice lanes
// butterfly-reduce so all return the full sdf (bit-identical across slices).
__device__ __forceinline__ void sdf_eval2(
    float p0x, float p0y, float p0z,
    float p1x, float p1y, float p1z,
    int s, const Shared& sh, float& out0, float& out1)
{
    float acc0[32], acc1[32];
#pragma unroll
    for (int i = 0; i < 32; ++i) {
        float b = sh.B2[s * 32 + i];
        acc0[i] = b; acc1[i] = b;
    }
#pragma unroll 2
    for (int j = 0; j < HID; ++j) {
        float4 t1 = sh.T1[j];                 // broadcast (all lanes same addr)
        float ta = fmaf(p0x, t1.x, fmaf(p0y, t1.y, fmaf(p0z, t1.z, t1.w)));
        float tb = fmaf(p1x, t1.x, fmaf(p1y, t1.y, fmaf(p1z, t1.z, t1.w)));
        float h0 = softplus_f(ta);
        float h1 = softplus_f(tb);
        const float4* row = sh.W2v + j * 32 + s;
#pragma unroll
        for (int u = 0; u < 8; ++u) {
            float4 w = row[4 * u];            // quad lanes hit disjoint banks
            acc0[4*u+0] = fmaf(h0, w.x, acc0[4*u+0]);
            acc0[4*u+1] = fmaf(h0, w.y, acc0[4*u+1]);
            acc0[4*u+2] = fmaf(h0, w.z, acc0[4*u+2]);
            acc0[4*u+3] = fmaf(h0, w.w, acc0[4*u+3]);
            acc1[4*u+0] = fmaf(h1, w.x, acc1[4*u+0]);
            acc1[4*u+1] = fmaf(h1, w.y, acc1[4*u+1]);
            acc1[4*u+2] = fmaf(h1, w.z, acc1[4*u+2]);
            acc1[4*u+3] = fmaf(h1, w.w, acc1[4*u+3]);
        }
    }
    float d0 = 0.f, d1 = 0.f;
#pragma unroll
    for (int i = 0; i < 32; ++i) {
        float w3 = sh.W3[s * 32 + i];
        d0 = fmaf(softplus_f(acc0[i]), w3, d0);
        d1 = fmaf(softplus_f(acc1[i]), w3, d1);
    }
    // butterfly over the 4 slice lanes; commutative adds -> identical bits
    d0 += __shfl_xor(d0, 1); d0 += __shfl_xor(d0, 2);
    d1 += __shfl_xor(d1, 1); d1 += __shfl_xor(d1, 2);
    out0 = d0 + sh.b3;
    out1 = d1 + sh.b3;
}

__global__ __launch_bounds__(512, 2)
void sphere_trace_kernel(const float* __restrict__ rays_d,
                         const float* __restrict__ rays_o,
                         const float* __restrict__ W1, const float* __restrict__ b1,
                         const float* __restrict__ W2, const float* __restrict__ b2,
                         const float* __restrict__ W3, const float* __restrict__ b3,
                         float* __restrict__ out)
{
    __shared__ float4 sT1[HID];
    __shared__ float  sW2[HID * HID];   // swizzled layout
    __shared__ float  sB2[HID];
    __shared__ float  sW3[HID];
    __shared__ float  sB3;

    const int tid = threadIdx.x;
    // stage W2 with 16B-chunk swizzle: k = s*32 + u*4 + e  ->  float idx j*128 + u*16 + s*4 + e
    for (int i = tid; i < HID * HID; i += 512) {
        float v = W2[i];
        int j = i >> 7, k = i & 127;
        int sl = k >> 5, r = k & 31, u = r >> 2, e = k & 3;
        sW2[j * 128 + u * 16 + sl * 4 + e] = v;
    }
    if (tid < HID) {
        sT1[tid] = make_float4(W1[tid], W1[HID + tid], W1[2 * HID + tid], b1[tid]);
        sB2[tid] = b2[tid];
        sW3[tid] = W3[tid];
    }
    if (tid == 0) sB3 = b3[0];
    __syncthreads();

    Shared sh;
    sh.T1 = sT1; sh.W2v = reinterpret_cast<const float4*>(sW2);
    sh.B2 = sB2; sh.W3 = sW3; sh.b3 = sB3;

    const int g   = blockIdx.x * 512 + tid;
    const int ray = g >> 2;          // 4 lanes per ray
    const int s   = g & 3;           // k-slice

    const float dx = rays_d[ray * 3 + 0];
    const float dy = rays_d[ray * 3 + 1];
    const float dz = rays_d[ray * 3 + 2];
    const float ox = rays_o[ray * 3 + 0];
    const float oy = rays_o[ray * 3 + 1];
    const float oz = rays_o[ray * 3 + 2];

    float z0 = 0.f, z1 = 0.f;        // ch0 sign=+1, ch1 sign=-1
    bool  m0 = true, m1 = true;
    float px0 = ox, py0 = oy, pz0 = oz;
    float px1 = ox, py1 = oy, pz1 = oz;

    float next0, next1;
    sdf_eval2(ox, oy, oz, ox, oy, oz, s, sh, next0, next1);

    for (int it = 0; it < NITER; ++it) {
        float sv0 = m0 ? next0 : 0.f;  sv0 = (sv0 <= THRS) ? 0.f : sv0;
        float sv1 = m1 ? next1 : 0.f;  sv1 = (sv1 <= THRS) ? 0.f : sv1;
        m0 = m0 && (sv0 > THRS);
        m1 = m1 && (sv1 > THRS);
        z0 += sv0;
        z1 -= sv1;

        px0 = fmaf(z0, dx, ox); py0 = fmaf(z0, dy, oy); pz0 = fmaf(z0, dz, oz);
        px1 = fmaf(z1, dx, ox); py1 = fmaf(z1, dy, oy); pz1 = fmaf(z1, dz, oz);

        float e0 = 0.f, e1 = 0.f;
        if (__ballot(m0 || m1) != 0ULL) {
            sdf_eval2(px0, py0, pz0, px1, py1, pz1, s, sh, e0, e1);
        }
        next0 = m0 ? e0 : 0.f;
        next1 = m1 ? e1 : 0.f;

        bool fm0 = next0 < 0.f;
        bool fm1 = next1 < 0.f;
        float step = 0.5f;
        for (int fi = 0; fi < NFIX; ++fi) {
            if (__ballot(fm0 || fm1) != 0ULL) {
                float z0f = fmaf(-step, sv0, z0);   // sign=+1
                float z1f = fmaf(+step, sv1, z1);   // sign=-1
                z0 = fm0 ? z0f : z0;
                z1 = fm1 ? z1f : z1;
                px0 = fmaf(z0, dx, ox); py0 = fmaf(z0, dy, oy); pz0 = fmaf(z0, dz, oz);
                px1 = fmaf(z1, dx, ox); py1 = fmaf(z1, dy, oy); pz1 = fmaf(z1, dz, oz);
                float f0, f1;
                sdf_eval2(px0, py0, pz0, px1, py1, pz1, s, sh, f0, f1);
                next0 = fm0 ? f0 : next0;
                next1 = fm1 ? f1 : next1;
                fm0 = next0 < 0.f;
                fm1 = next1 < 0.f;
            }
            step *= 0.5f;
        }

        bool pair = (z0 < z1);
        m0 = m0 && pair;
        m1 = m1 && pair;
    }

    // final top-of-loop mask update
    float sv0 = m0 ? next0 : 0.f;  sv0 = (sv0 <= THRS) ? 0.f : sv0;
    float sv1 = m1 ? next1 : 0.f;  sv1 = (sv1 <= THRS) ? 0.f : sv1;
    m0 = m0 && (sv0 > THRS);
    m1 = m1 && (sv1 > THRS);

    if (s == 0) {
        // outputs: points (2,N,3), z (2,N), mask (2,N) concatenated flat
        const size_t pb = (size_t)ray * 3;
        out[pb + 0] = px0;
        out[pb + 1] = py0;
        out[pb + 2] = pz0;
        out[(size_t)NRAYS * 3 + pb + 0] = px1;
        out[(size_t)NRAYS * 3 + pb + 1] = py1;
        out[(size_t)NRAYS * 3 + pb + 2] = pz1;
        out[2 * NRAYS * 3 + ray]            = z0;
        out[2 * NRAYS * 3 + NRAYS + ray]    = z1;
        out[2 * NRAYS * 3 + 2 * NRAYS + ray]         = m0 ? 1.0f : 0.0f;
        out[2 * NRAYS * 3 + 2 * NRAYS + NRAYS + ray] = m1 ? 1.0f : 0.0f;
    }
}

extern "C" void kernel_launch(void* const* d_in, const int* in_sizes, int n_in,
                              void* d_out, int out_size, void* d_ws, size_t ws_size,
                              hipStream_t stream) {
    const float* rays_d = (const float*)d_in[0];
    const float* rays_o = (const float*)d_in[1];
    const float* W1 = (const float*)d_in[2];
    const float* b1 = (const float*)d_in[3];
    const float* W2 = (const float*)d_in[4];
    const float* b2 = (const float*)d_in[5];
    const float* W3 = (const float*)d_in[6];
    const float* b3 = (const float*)d_in[7];
    float* out = (float*)d_out;

    // 32768 rays x 4 slice-lanes = 131072 threads = 256 blocks x 512
    const int block = 512;
    const int grid  = (NRAYS * 4) / block;

    sphere_trace_kernel<<<grid, block, 0, stream>>>(
        rays_d, rays_o, W1, b1, W2, b2, W3, b3, out);
}

// Round 4
// 201.075 us; speedup vs baseline: 1.4866x; 1.4003x over previous
//
#include <hip/hip_runtime.h>

#define NRAYS 32768
#define THRS  5e-5f

typedef float f32x4 __attribute__((ext_vector_type(4)));
typedef short s16x8 __attribute__((ext_vector_type(8)));

// ---- LDS byte-offset map (total 152592 B, 1 block/CU) ----
// W2 splits, fragment-order: region(split s, coltile ct 0..7, kslice kb 0..3) = 1024 B
#define WB(s,ct,kb)  ((((s)*8+(ct))*4+(kb))*1024)
// H (layer-1 activations) splits, fragment-order: region(split, mtile 0..3, kslice 0..3)
#define HBASE        98304
#define HB(s,mt,kb)  (HBASE + (((s)*4+(mt))*4+(kb))*1024)
#define T1B 147456   // float4[128] = (W1x,W1y,W1z,b1)
#define B2B 149504   // float[128]
#define W3B 150016   // float[128]
#define B3B 150528   // float
#define PXB 150544   // float[64] current point x
#define PYB 150800
#define PZB 151056
#define ZSB 151312   // float[64] current z
#define PARTB 151568 // float[4][64] layer-3 partials per wave
#define LDSZ 152592

__device__ __forceinline__ float softplus_f(float x){
  return fmaxf(x, 0.0f) + log1pf(expf(-fabsf(x)));
}
__device__ __forceinline__ unsigned short bf16rne(float x){
  unsigned int u = __float_as_uint(x);
  unsigned int r = u + 0x7fffu + ((u >> 16) & 1u);
  return (unsigned short)(r >> 16);
}
__device__ __forceinline__ float bf16tof(unsigned short h){
  return __uint_as_float(((unsigned int)h) << 16);
}

// Full 64-row MLP eval. All 256 threads participate; rows' points in sm[P*B].
// Returns sdf for row t (valid for t<64 only). Contains internal barriers.
__device__ __forceinline__ float eval_block(unsigned char* sm, int t){
  __syncthreads();                       // points / previous phase visible
  const int lane = t & 63;
  const int wave = t >> 6;

  // ---------- Layer 1 (fp32) + 3-way bf16 split, written in A-fragment order.
  {
    const int row = lane;                // this thread's batch row
    const float px = ((const float*)(sm+PXB))[row];
    const float py = ((const float*)(sm+PYB))[row];
    const float pz = ((const float*)(sm+PZB))[row];
    const int mt  = row >> 4;
    const int r15 = row & 15;
#pragma unroll
    for (int c = 0; c < 4; ++c){         // 4 chunks of 8 k-units
      s16x8 vh, vm, vl;
#pragma unroll
      for (int u = 0; u < 8; ++u){
        const int k = wave*32 + c*8 + u; // wave-uniform k -> broadcast read
        const float4 t1 = ((const float4*)(sm+T1B))[k];
        const float pre = fmaf(px, t1.x, fmaf(py, t1.y, fmaf(pz, t1.z, t1.w)));
        const float h = softplus_f(pre);
        const unsigned short uh = bf16rne(h);
        const float r1 = h - bf16tof(uh);
        const unsigned short um = bf16rne(r1);
        const float r2 = r1 - bf16tof(um);
        const unsigned short ul = bf16rne(r2);
        vh[u] = (short)uh; vm[u] = (short)um; vl[u] = (short)ul;
      }
      const int slot = (c*16 + r15)*16;  // fragment lane-slot byte offset
      *(s16x8*)(sm + HB(0,mt,wave) + slot) = vh;
      *(s16x8*)(sm + HB(1,mt,wave) + slot) = vm;
      *(s16x8*)(sm + HB(2,mt,wave) + slot) = vl;
    }
  }
  __syncthreads();                       // H complete

  // ---------- Layer 2: C = H @ W2 via MFMA, bf16x3 (6 products, err ~2^-27)
  f32x4 acc[4][2];
#pragma unroll
  for (int mt=0; mt<4; ++mt)
#pragma unroll
    for (int ct=0; ct<2; ++ct){
      f32x4 zv = {0.f, 0.f, 0.f, 0.f};
      acc[mt][ct] = zv;
    }
#pragma unroll
  for (int kb = 0; kb < 4; ++kb){
    s16x8 A0[4], A1[4], A2[4], B0[2], B1[2], B2w[2];
#pragma unroll
    for (int mt=0; mt<4; ++mt){
      A0[mt] = *(const s16x8*)(sm + HB(0,mt,kb) + lane*16);
      A1[mt] = *(const s16x8*)(sm + HB(1,mt,kb) + lane*16);
      A2[mt] = *(const s16x8*)(sm + HB(2,mt,kb) + lane*16);
    }
#pragma unroll
    for (int ct=0; ct<2; ++ct){
      const int ctg = wave*2 + ct;       // this wave's 32-col stripe
      B0[ct]  = *(const s16x8*)(sm + WB(0,ctg,kb) + lane*16);
      B1[ct]  = *(const s16x8*)(sm + WB(1,ctg,kb) + lane*16);
      B2w[ct] = *(const s16x8*)(sm + WB(2,ctg,kb) + lane*16);
    }
#pragma unroll
    for (int mt=0; mt<4; ++mt){
#pragma unroll
      for (int ct=0; ct<2; ++ct){
        f32x4 a = acc[mt][ct];
        a = __builtin_amdgcn_mfma_f32_16x16x32_bf16(A0[mt], B0[ct],  a, 0,0,0);
        a = __builtin_amdgcn_mfma_f32_16x16x32_bf16(A0[mt], B1[ct],  a, 0,0,0);
        a = __builtin_amdgcn_mfma_f32_16x16x32_bf16(A1[mt], B0[ct],  a, 0,0,0);
        a = __builtin_amdgcn_mfma_f32_16x16x32_bf16(A0[mt], B2w[ct], a, 0,0,0);
        a = __builtin_amdgcn_mfma_f32_16x16x32_bf16(A1[mt], B1[ct],  a, 0,0,0);
        a = __builtin_amdgcn_mfma_f32_16x16x32_bf16(A2[mt], B0[ct],  a, 0,0,0);
        acc[mt][ct] = a;
      }
    }
  }

  // ---------- Layer 3: sdf[row] = sum_col sp(C+b2)*W3 + b3
  const int l15 = lane & 15, l4 = lane >> 4;
  float b2v[2], w3v[2];
#pragma unroll
  for (int ct=0; ct<2; ++ct){
    const int col = (wave*2+ct)*16 + l15;
    b2v[ct] = ((const float*)(sm+B2B))[col];
    w3v[ct] = ((const float*)(sm+W3B))[col];
  }
#pragma unroll
  for (int mt=0; mt<4; ++mt){
#pragma unroll
    for (int i=0; i<4; ++i){
      // C layout (m89-verified): row = mt*16 + l4*4 + i, col = stripe + l15
      float v = softplus_f(acc[mt][0][i] + b2v[0]) * w3v[0]
              + softplus_f(acc[mt][1][i] + b2v[1]) * w3v[1];
      v += __shfl_xor(v, 1);
      v += __shfl_xor(v, 2);
      v += __shfl_xor(v, 4);
      v += __shfl_xor(v, 8);             // reduce over the 16 col-lanes
      if (l15 == 0)
        ((float*)(sm+PARTB))[wave*64 + mt*16 + l4*4 + i] = v;
    }
  }
  __syncthreads();
  float r = 0.f;
  if (t < 64){
    const float* part = (const float*)(sm+PARTB);
    r = (part[t] + part[64+t]) + (part[128+t] + part[192+t])
        + *((const float*)(sm+B3B));
  }
  return r;
}

__global__ __launch_bounds__(256, 1)
void trace_kernel(const float* __restrict__ rays_d, const float* __restrict__ rays_o,
                  const float* __restrict__ W1, const float* __restrict__ b1,
                  const float* __restrict__ W2, const float* __restrict__ b2,
                  const float* __restrict__ W3, const float* __restrict__ b3,
                  float* __restrict__ out)
{
  __shared__ __align__(16) unsigned char sm[LDSZ];
  const int t = threadIdx.x;

  // ---- stage weights: W2 -> 3 bf16 split planes in B-fragment order
  for (int e = t; e < 16384; e += 256){
    const int j = e >> 7, k = e & 127;   // W2[j][k]: j = K-dim, k = out col
    const float w = W2[e];
    const unsigned short uh = bf16rne(w);
    const float r1 = w - bf16tof(uh);
    const unsigned short um = bf16rne(r1);
    const float r2 = r1 - bf16tof(um);
    const unsigned short ul = bf16rne(r2);
    const int off = (((j>>3)&3)*16 + (k&15))*16 + (j&7)*2;
    *(unsigned short*)(sm + WB(0, k>>4, j>>5) + off) = uh;
    *(unsigned short*)(sm + WB(1, k>>4, j>>5) + off) = um;
    *(unsigned short*)(sm + WB(2, k>>4, j>>5) + off) = ul;
  }
  if (t < 128){
    ((float4*)(sm+T1B))[t] = make_float4(W1[t], W1[128+t], W1[256+t], b1[t]);
    ((float*)(sm+B2B))[t] = b2[t];
    ((float*)(sm+W3B))[t] = W3[t];
  }
  if (t == 0) *((float*)(sm+B3B)) = b3[0];

  // ---- per-channel state (threads 0..63 are the logic threads)
  const bool isL = (t < 64);
  const int chan = blockIdx.x * 64 + t;
  const int ray  = chan >> 1;
  const int c01  = chan & 1;
  const float sgn = c01 ? -1.0f : 1.0f;
  float dx=0,dy=0,dz=0,ox=0,oy=0,oz=0;
  if (isL){
    dx = rays_d[ray*3+0]; dy = rays_d[ray*3+1]; dz = rays_d[ray*3+2];
    ox = rays_o[ray*3+0]; oy = rays_o[ray*3+1]; oz = rays_o[ray*3+2];
    ((float*)(sm+PXB))[t] = ox;
    ((float*)(sm+PYB))[t] = oy;
    ((float*)(sm+PZB))[t] = oz;
    ((float*)(sm+ZSB))[t] = 0.f;
  }

  float nxt = eval_block(sm, t);         // initial sdf at origins
  float z = 0.f, next_sdf = nxt, sv = 0.f;
  bool m = true;

  for (int it = 0; it < 6; ++it){
    if (isL){
      sv = m ? next_sdf : 0.f;
      sv = (sv <= THRS) ? 0.f : sv;
      m = m && (sv > THRS);
      z = fmaf(sgn, sv, z);
      ((float*)(sm+PXB))[t] = fmaf(z, dx, ox);
      ((float*)(sm+PYB))[t] = fmaf(z, dy, oy);
      ((float*)(sm+PZB))[t] = fmaf(z, dz, oz);
      ((float*)(sm+ZSB))[t] = z;
    }
    const int need = __syncthreads_or(isL && m);
    if (need){
      nxt = eval_block(sm, t);
      if (isL) next_sdf = m ? nxt : 0.f;
    } else {
      if (isL) next_sdf = 0.f;
    }
    bool fm = isL ? (next_sdf < 0.f) : false;
    float step = 0.5f;
    for (int fi = 0; fi < 3; ++fi){
      const int needf = __syncthreads_or((int)fm);
      if (needf){
        if (fm){
          z = fmaf(-step*sgn, sv, z);
          ((float*)(sm+PXB))[t] = fmaf(z, dx, ox);
          ((float*)(sm+PYB))[t] = fmaf(z, dy, oy);
          ((float*)(sm+PZB))[t] = fmaf(z, dz, oz);
          ((float*)(sm+ZSB))[t] = z;
        }
        nxt = eval_block(sm, t);
        if (isL){
          if (fm) next_sdf = nxt;
          fm = next_sdf < 0.f;
        }
      }
      step *= 0.5f;
    }
    __syncthreads();                     // z writes visible for pair check
    if (isL){
      const float zo = ((const float*)(sm+ZSB))[t^1];
      const bool pair = c01 ? (zo < z) : (z < zo);
      m = m && pair;
    }
    __syncthreads();                     // pair-reads done before next-iter writes
  }

  if (isL){
    sv = m ? next_sdf : 0.f;
    sv = (sv <= THRS) ? 0.f : sv;
    m = m && (sv > THRS);
    const float px = fmaf(z, dx, ox);
    const float py = fmaf(z, dy, oy);
    const float pz = fmaf(z, dz, oz);
    // outputs: points (2,N,3), z (2,N), mask (2,N) flat
    const size_t pb = (size_t)c01 * NRAYS * 3 + (size_t)ray * 3;
    out[pb+0] = px; out[pb+1] = py; out[pb+2] = pz;
    out[2*NRAYS*3 + (size_t)c01*NRAYS + ray] = z;
    out[2*NRAYS*3 + 2*NRAYS + (size_t)c01*NRAYS + ray] = m ? 1.f : 0.f;
  }
}

extern "C" void kernel_launch(void* const* d_in, const int* in_sizes, int n_in,
                              void* d_out, int out_size, void* d_ws, size_t ws_size,
                              hipStream_t stream) {
  const float* rays_d = (const float*)d_in[0];
  const float* rays_o = (const float*)d_in[1];
  const float* W1 = (const float*)d_in[2];
  const float* b1 = (const float*)d_in[3];
  const float* W2 = (const float*)d_in[4];
  const float* b2 = (const float*)d_in[5];
  const float* W3 = (const float*)d_in[6];
  const float* b3 = (const float*)d_in[7];
  float* out = (float*)d_out;
  (void)d_ws; (void)ws_size;

  // 65536 ray-channels / 64 per block = 1024 blocks x 256 threads
  trace_kernel<<<1024, 256, 0, stream>>>(
      rays_d, rays_o, W1, b1, W2, b2, W3, b3, out);
}

// Round 5
// 142.167 us; speedup vs baseline: 2.1026x; 1.4144x over previous
//
#include <hip/hip_runtime.h>

#define NRAYS 32768
#define THRS  5e-5f

typedef float f32x4 __attribute__((ext_vector_type(4)));
typedef short s16x8 __attribute__((ext_vector_type(8)));

// ---- LDS byte map (105488 B total, 1 block/CU) ----
// W2 3-split bf16, B-fragment order: region(split s, coltile ct 0..7, kslice kb 0..3)
#define WB(s,ct,kb) ((((s)*8+(ct))*4+(kb))*1024)
#define T1B  98304   // float4[128] = (W1x,W1y,W1z,b1)
#define B2B  100352  // float[128]
#define W3B  100864  // float[128]
#define B3B  101376  // float (padded to 16)
#define PXB  101392  // float[256]
#define PYB  102416
#define PZB  103440
#define SDFB 104464  // float[256]
#define LDSZ 105488

__device__ __forceinline__ float softplus_f(float x){
  return fmaxf(x, 0.0f) + log1pf(expf(-fabsf(x)));
}
__device__ __forceinline__ unsigned short bf16rne(float x){
  unsigned int u = __float_as_uint(x);
  unsigned int r = u + 0x7fffu + ((u >> 16) & 1u);
  return (unsigned short)(r >> 16);
}
__device__ __forceinline__ float bf16tof(unsigned short h){
  return __uint_as_float(((unsigned int)h) << 16);
}

// Batched M=256 MLP eval. All 256 threads participate. Wave w owns rows
// w*64..w*64+63; A-fragments (layer1 + 3-split) built directly in registers.
// Caller must have a barrier between point-writes and this call.
__device__ __forceinline__ float eval_block(unsigned char* sm, int t){
  const int lane = t & 63;
  const int wave = t >> 6;
  const int l15  = lane & 15;
  const int lhi  = lane >> 4;

  // my 4 row-tiles' points (broadcast LDS reads)
  float prx[4], pry[4], prz[4];
#pragma unroll
  for (int mt = 0; mt < 4; ++mt){
    const int row = wave*64 + mt*16 + l15;
    prx[mt] = ((const float*)(sm+PXB))[row];
    pry[mt] = ((const float*)(sm+PYB))[row];
    prz[mt] = ((const float*)(sm+PZB))[row];
  }

  f32x4 acc[4][8];
#pragma unroll
  for (int mt = 0; mt < 4; ++mt)
#pragma unroll
    for (int ct = 0; ct < 8; ++ct){
      f32x4 zv = {0.f,0.f,0.f,0.f};
      acc[mt][ct] = zv;
    }

#pragma unroll
  for (int kb = 0; kb < 4; ++kb){
    // ---- layer 1 for this k-slice, 3-way bf16 split, in A-frag order
    s16x8 A0[4], A1[4], A2[4];
#pragma unroll
    for (int u = 0; u < 8; ++u){
      const int k = kb*32 + lhi*8 + u;          // per-lane k
      const float4 t1 = ((const float4*)(sm+T1B))[k];
#pragma unroll
      for (int mt = 0; mt < 4; ++mt){
        const float pre = fmaf(prx[mt], t1.x,
                          fmaf(pry[mt], t1.y,
                          fmaf(prz[mt], t1.z, t1.w)));
        const float h = softplus_f(pre);
        const unsigned short uh = bf16rne(h);
        const float r1 = h - bf16tof(uh);
        const unsigned short um = bf16rne(r1);
        const float r2 = r1 - bf16tof(um);
        const unsigned short ul = bf16rne(r2);
        A0[mt][u] = (short)uh; A1[mt][u] = (short)um; A2[mt][u] = (short)ul;
      }
    }
    // ---- layer 2: 6-product bf16x3 MFMA (err ~2^-27), all 8 col-tiles
#pragma unroll
    for (int ct = 0; ct < 8; ++ct){
      const s16x8 B0  = *(const s16x8*)(sm + WB(0,ct,kb) + lane*16);
      const s16x8 B1  = *(const s16x8*)(sm + WB(1,ct,kb) + lane*16);
      const s16x8 B2w = *(const s16x8*)(sm + WB(2,ct,kb) + lane*16);
#pragma unroll
      for (int mt = 0; mt < 4; ++mt){
        f32x4 a = acc[mt][ct];
        a = __builtin_amdgcn_mfma_f32_16x16x32_bf16(A0[mt], B0,  a, 0,0,0);
        a = __builtin_amdgcn_mfma_f32_16x16x32_bf16(A0[mt], B1,  a, 0,0,0);
        a = __builtin_amdgcn_mfma_f32_16x16x32_bf16(A1[mt], B0,  a, 0,0,0);
        a = __builtin_amdgcn_mfma_f32_16x16x32_bf16(A0[mt], B2w, a, 0,0,0);
        a = __builtin_amdgcn_mfma_f32_16x16x32_bf16(A1[mt], B1,  a, 0,0,0);
        a = __builtin_amdgcn_mfma_f32_16x16x32_bf16(A2[mt], B0,  a, 0,0,0);
        acc[mt][ct] = a;
      }
    }
  }

  // ---- layer 3: sdf[row] = sum_col sp(C+b2)*W3 (+b3 by caller-read)
  float b2v[8], w3v[8];
#pragma unroll
  for (int ct = 0; ct < 8; ++ct){
    const int col = ct*16 + l15;
    b2v[ct] = ((const float*)(sm+B2B))[col];
    w3v[ct] = ((const float*)(sm+W3B))[col];
  }
#pragma unroll
  for (int mt = 0; mt < 4; ++mt){
#pragma unroll
    for (int i = 0; i < 4; ++i){
      // C layout (m89-verified): row = mt*16 + lhi*4 + i, col = ct*16 + l15
      float v = 0.f;
#pragma unroll
      for (int ct = 0; ct < 8; ++ct)
        v = fmaf(softplus_f(acc[mt][ct][i] + b2v[ct]), w3v[ct], v);
      v += __shfl_xor(v, 1);
      v += __shfl_xor(v, 2);
      v += __shfl_xor(v, 4);
      v += __shfl_xor(v, 8);                     // reduce over 16 col-lanes
      if (l15 == 0)
        ((float*)(sm+SDFB))[wave*64 + mt*16 + lhi*4 + i] = v;
    }
  }
  __syncthreads();
  return ((const float*)(sm+SDFB))[t] + *((const float*)(sm+B3B));
}

__global__ __launch_bounds__(256, 1)
void trace_kernel(const float* __restrict__ rays_d, const float* __restrict__ rays_o,
                  const float* __restrict__ W1, const float* __restrict__ b1,
                  const float* __restrict__ W2, const float* __restrict__ b2,
                  const float* __restrict__ W3, const float* __restrict__ b3,
                  float* __restrict__ out)
{
  __shared__ __align__(16) unsigned char sm[LDSZ];
  const int t = threadIdx.x;

  // ---- stage W2: 3-split bf16, B-fragment order, conflict-free b128 writes.
  // slot si -> (col k, j-octet); 8 consecutive j's pack into one s16x8.
  for (int si = t; si < 2048; si += 256){
    const int k    = si & 127;
    const int joct = si >> 7;
    s16x8 vh, vm, vl;
#pragma unroll
    for (int jj = 0; jj < 8; ++jj){
      const float w = W2[(joct*8 + jj)*128 + k];   // coalesced over lanes (k)
      const unsigned short uh = bf16rne(w);
      const float r1 = w - bf16tof(uh);
      const unsigned short um = bf16rne(r1);
      const float r2 = r1 - bf16tof(um);
      const unsigned short ul = bf16rne(r2);
      vh[jj] = (short)uh; vm[jj] = (short)um; vl[jj] = (short)ul;
    }
    const int ct = k >> 4, kb = joct >> 2;
    const int slot = ((joct & 3)*16 + (k & 15))*16;
    *(s16x8*)(sm + WB(0,ct,kb) + slot) = vh;
    *(s16x8*)(sm + WB(1,ct,kb) + slot) = vm;
    *(s16x8*)(sm + WB(2,ct,kb) + slot) = vl;
  }
  if (t < 128){
    ((float4*)(sm+T1B))[t] = make_float4(W1[t], W1[128+t], W1[256+t], b1[t]);
    ((float*)(sm+B2B))[t] = b2[t];
    ((float*)(sm+W3B))[t] = W3[t];
  }
  if (t == 0) *((float*)(sm+B3B)) = b3[0];

  // ---- per-channel trace state: thread t owns channel blockIdx*256 + t
  const int chan = blockIdx.x * 256 + t;
  const int ray  = chan >> 1;
  const int c01  = chan & 1;
  const float sgn = c01 ? -1.0f : 1.0f;

  const float dx = rays_d[ray*3+0], dy = rays_d[ray*3+1], dz = rays_d[ray*3+2];
  const float ox = rays_o[ray*3+0], oy = rays_o[ray*3+1], oz = rays_o[ray*3+2];

  ((float*)(sm+PXB))[t] = ox;
  ((float*)(sm+PYB))[t] = oy;
  ((float*)(sm+PZB))[t] = oz;
  __syncthreads();

  float next_sdf = eval_block(sm, t);   // sdf at origins
  float z = 0.f, sv = 0.f;
  float px = ox, py = oy, pz = oz;
  bool m = true;

  for (int it = 0; it < 6; ++it){
    sv = m ? next_sdf : 0.f;
    sv = (sv <= THRS) ? 0.f : sv;
    m = m && (sv > THRS);
    z = fmaf(sgn, sv, z);
    px = fmaf(z, dx, ox); py = fmaf(z, dy, oy); pz = fmaf(z, dz, oz);
    ((float*)(sm+PXB))[t] = px;
    ((float*)(sm+PYB))[t] = py;
    ((float*)(sm+PZB))[t] = pz;

    const int need = __syncthreads_or((int)m);   // barrier: points visible
    if (need){
      const float e = eval_block(sm, t);
      next_sdf = m ? e : 0.f;
    } else {
      next_sdf = 0.f;
    }

    bool fm = next_sdf < 0.f;
    float step = 0.5f;
    for (int fi = 0; fi < 3; ++fi){
      const int needf = __syncthreads_or((int)fm);
      if (needf){
        if (fm){
          z = fmaf(-step*sgn, sv, z);
          px = fmaf(z, dx, ox); py = fmaf(z, dy, oy); pz = fmaf(z, dz, oz);
          ((float*)(sm+PXB))[t] = px;
          ((float*)(sm+PYB))[t] = py;
          ((float*)(sm+PZB))[t] = pz;
        }
        const float f = eval_block(sm, t);
        if (fm) next_sdf = f;
        fm = next_sdf < 0.f;
      }
      step *= 0.5f;
    }

    // cross-channel coupling: adjacent thread holds the sibling channel
    const float zo = __shfl_xor(z, 1);
    const bool pair = c01 ? (zo < z) : (z < zo);
    m = m && pair;

    // all-dead fixed-point: remaining iterations are exact no-ops
    if (!__syncthreads_or((int)m)) break;
  }

  // final top-of-loop mask update
  sv = m ? next_sdf : 0.f;
  sv = (sv <= THRS) ? 0.f : sv;
  m = m && (sv > THRS);

  // outputs: points (2,N,3), z (2,N), mask (2,N) flat
  const size_t pb = (size_t)c01 * NRAYS * 3 + (size_t)ray * 3;
  out[pb+0] = px; out[pb+1] = py; out[pb+2] = pz;
  out[2*NRAYS*3 + (size_t)c01*NRAYS + ray] = z;
  out[2*NRAYS*3 + 2*NRAYS + (size_t)c01*NRAYS + ray] = m ? 1.f : 0.f;
}

extern "C" void kernel_launch(void* const* d_in, const int* in_sizes, int n_in,
                              void* d_out, int out_size, void* d_ws, size_t ws_size,
                              hipStream_t stream) {
  const float* rays_d = (const float*)d_in[0];
  const float* rays_o = (const float*)d_in[1];
  const float* W1 = (const float*)d_in[2];
  const float* b1 = (const float*)d_in[3];
  const float* W2 = (const float*)d_in[4];
  const float* b2 = (const float*)d_in[5];
  const float* W3 = (const float*)d_in[6];
  const float* b3 = (const float*)d_in[7];
  float* out = (float*)d_out;
  (void)d_ws; (void)ws_size;

  // 65536 ray-channels / 256 per block = 256 blocks = 1 per CU, single round
  trace_kernel<<<256, 256, 0, stream>>>(
      rays_d, rays_o, W1, b1, W2, b2, W3, b3, out);
}

// Round 6
// 38.010 us; speedup vs baseline: 7.8641x; 3.7403x over previous
//
#include <hip/hip_runtime.h>

#define NRAYS 32768
#define THRS  5e-5f

typedef float f32x4 __attribute__((ext_vector_type(4)));
typedef short s16x8 __attribute__((ext_vector_type(8)));

// ---- LDS byte map (105488 B total, 1 block/CU) ----
// W2 3-split bf16, B-fragment order: region(split s, coltile ct 0..7, kslice kb 0..3)
#define WB(s,ct,kb) ((((s)*8+(ct))*4+(kb))*1024)
#define T1B  98304   // float4[128] = (W1x,W1y,W1z,b1)
#define B2B  100352  // float[128]
#define W3B  100864  // float[128]
#define B3B  101376  // float (padded to 16)
#define PXB  101392  // float[256]
#define PYB  102416
#define PZB  103440
#define SDFB 104464  // float[256]
#define LDSZ 105488

// Cheap softplus: max(x,0) + ln2 * log2(1 + 2^(-|x|*log2e)).
// v_exp_f32 / v_log_f32 are ~1ulp; abs err ~6e-8 (same order as libm path).
__device__ __forceinline__ float softplus_f(float x){
  const float L2E = 1.44269504088896340f;
  const float LN2 = 0.69314718055994531f;
  float y = __builtin_amdgcn_exp2f(-fabsf(x) * L2E);
  float l = __builtin_amdgcn_logf(1.0f + y);      // log2(1+y)
  return fmaf(LN2, l, fmaxf(x, 0.0f));
}

__device__ __forceinline__ float bf16tof(unsigned short h){
  return __uint_as_float(((unsigned int)h) << 16);
}
// Truncation 3-way bf16 split: h = a0+a1+a2 + r, |r| <~ 2^-24|h|.
// Each subtraction is exact (high-bits split), ~7 VALU ops total.
__device__ __forceinline__ void split3(float h, unsigned short& a0,
                                       unsigned short& a1, unsigned short& a2){
  a0 = (unsigned short)(__float_as_uint(h) >> 16);
  const float r1 = h - bf16tof(a0);
  a1 = (unsigned short)(__float_as_uint(r1) >> 16);
  const float r2 = r1 - bf16tof(a1);
  a2 = (unsigned short)(__float_as_uint(r2) >> 16);
}

// Batched M=256 MLP eval. All 256 threads participate. Wave w owns rows
// w*64..w*64+63; A-fragments (layer1 + 3-split) built directly in registers.
// Caller must have a barrier between point-writes and this call.
__device__ __forceinline__ float eval_block(unsigned char* sm, int t){
  const int lane = t & 63;
  const int wave = t >> 6;
  const int l15  = lane & 15;
  const int lhi  = lane >> 4;

  // my 4 row-tiles' points (broadcast LDS reads)
  float prx[4], pry[4], prz[4];
#pragma unroll
  for (int mt = 0; mt < 4; ++mt){
    const int row = wave*64 + mt*16 + l15;
    prx[mt] = ((const float*)(sm+PXB))[row];
    pry[mt] = ((const float*)(sm+PYB))[row];
    prz[mt] = ((const float*)(sm+PZB))[row];
  }

  f32x4 acc[4][8];
#pragma unroll
  for (int mt = 0; mt < 4; ++mt)
#pragma unroll
    for (int ct = 0; ct < 8; ++ct){
      f32x4 zv = {0.f,0.f,0.f,0.f};
      acc[mt][ct] = zv;
    }

#pragma unroll
  for (int kb = 0; kb < 4; ++kb){
    // ---- layer 1 for this k-slice, 3-way bf16 trunc-split, A-frag order
    s16x8 A0[4], A1[4], A2[4];
#pragma unroll
    for (int u = 0; u < 8; ++u){
      const int k = kb*32 + lhi*8 + u;          // per-lane k
      const float4 t1 = ((const float4*)(sm+T1B))[k];
#pragma unroll
      for (int mt = 0; mt < 4; ++mt){
        const float pre = fmaf(prx[mt], t1.x,
                          fmaf(pry[mt], t1.y,
                          fmaf(prz[mt], t1.z, t1.w)));
        const float h = softplus_f(pre);
        unsigned short uh, um, ul;
        split3(h, uh, um, ul);
        A0[mt][u] = (short)uh; A1[mt][u] = (short)um; A2[mt][u] = (short)ul;
      }
    }
    // ---- layer 2: 6-product bf16x3 MFMA (err ~2^-24), all 8 col-tiles
#pragma unroll
    for (int ct = 0; ct < 8; ++ct){
      const s16x8 B0  = *(const s16x8*)(sm + WB(0,ct,kb) + lane*16);
      const s16x8 B1  = *(const s16x8*)(sm + WB(1,ct,kb) + lane*16);
      const s16x8 B2w = *(const s16x8*)(sm + WB(2,ct,kb) + lane*16);
#pragma unroll
      for (int mt = 0; mt < 4; ++mt){
        f32x4 a = acc[mt][ct];
        a = __builtin_amdgcn_mfma_f32_16x16x32_bf16(A0[mt], B0,  a, 0,0,0);
        a = __builtin_amdgcn_mfma_f32_16x16x32_bf16(A0[mt], B1,  a, 0,0,0);
        a = __builtin_amdgcn_mfma_f32_16x16x32_bf16(A1[mt], B0,  a, 0,0,0);
        a = __builtin_amdgcn_mfma_f32_16x16x32_bf16(A0[mt], B2w, a, 0,0,0);
        a = __builtin_amdgcn_mfma_f32_16x16x32_bf16(A1[mt], B1,  a, 0,0,0);
        a = __builtin_amdgcn_mfma_f32_16x16x32_bf16(A2[mt], B0,  a, 0,0,0);
        acc[mt][ct] = a;
      }
    }
  }

  // ---- layer 3: sdf[row] = sum_col sp(C+b2)*W3 (+b3 by caller-read)
  float b2v[8], w3v[8];
#pragma unroll
  for (int ct = 0; ct < 8; ++ct){
    const int col = ct*16 + l15;
    b2v[ct] = ((const float*)(sm+B2B))[col];
    w3v[ct] = ((const float*)(sm+W3B))[col];
  }
#pragma unroll
  for (int mt = 0; mt < 4; ++mt){
#pragma unroll
    for (int i = 0; i < 4; ++i){
      // C layout (m89-verified): row = mt*16 + lhi*4 + i, col = ct*16 + l15
      float v = 0.f;
#pragma unroll
      for (int ct = 0; ct < 8; ++ct)
        v = fmaf(softplus_f(acc[mt][ct][i] + b2v[ct]), w3v[ct], v);
      v += __shfl_xor(v, 1);
      v += __shfl_xor(v, 2);
      v += __shfl_xor(v, 4);
      v += __shfl_xor(v, 8);                     // reduce over 16 col-lanes
      if (l15 == 0)
        ((float*)(sm+SDFB))[wave*64 + mt*16 + lhi*4 + i] = v;
    }
  }
  __syncthreads();
  return ((const float*)(sm+SDFB))[t] + *((const float*)(sm+B3B));
}

__global__ __launch_bounds__(256, 1)
void trace_kernel(const float* __restrict__ rays_d, const float* __restrict__ rays_o,
                  const float* __restrict__ W1, const float* __restrict__ b1,
                  const float* __restrict__ W2, const float* __restrict__ b2,
                  const float* __restrict__ W3, const float* __restrict__ b3,
                  float* __restrict__ out)
{
  __shared__ __align__(16) unsigned char sm[LDSZ];
  const int t = threadIdx.x;

  // ---- stage W2: 3-split bf16, B-fragment order, conflict-free b128 writes.
  for (int si = t; si < 2048; si += 256){
    const int k    = si & 127;
    const int joct = si >> 7;
    s16x8 vh, vm, vl;
#pragma unroll
    for (int jj = 0; jj < 8; ++jj){
      const float w = W2[(joct*8 + jj)*128 + k];   // coalesced over lanes (k)
      unsigned short uh, um, ul;
      split3(w, uh, um, ul);
      vh[jj] = (short)uh; vm[jj] = (short)um; vl[jj] = (short)ul;
    }
    const int ct = k >> 4, kb = joct >> 2;
    const int slot = ((joct & 3)*16 + (k & 15))*16;
    *(s16x8*)(sm + WB(0,ct,kb) + slot) = vh;
    *(s16x8*)(sm + WB(1,ct,kb) + slot) = vm;
    *(s16x8*)(sm + WB(2,ct,kb) + slot) = vl;
  }
  if (t < 128){
    ((float4*)(sm+T1B))[t] = make_float4(W1[t], W1[128+t], W1[256+t], b1[t]);
    ((float*)(sm+B2B))[t] = b2[t];
    ((float*)(sm+W3B))[t] = W3[t];
  }
  if (t == 0) *((float*)(sm+B3B)) = b3[0];

  // ---- per-channel trace state: thread t owns channel blockIdx*256 + t
  const int chan = blockIdx.x * 256 + t;
  const int ray  = chan >> 1;
  const int c01  = chan & 1;
  const float sgn = c01 ? -1.0f : 1.0f;

  const float dx = rays_d[ray*3+0], dy = rays_d[ray*3+1], dz = rays_d[ray*3+2];
  const float ox = rays_o[ray*3+0], oy = rays_o[ray*3+1], oz = rays_o[ray*3+2];

  ((float*)(sm+PXB))[t] = ox;
  ((float*)(sm+PYB))[t] = oy;
  ((float*)(sm+PZB))[t] = oz;
  __syncthreads();

  float next_sdf = eval_block(sm, t);   // sdf at origins
  float z = 0.f, sv = 0.f;
  float px = ox, py = oy, pz = oz;
  bool m = true;

  for (int it = 0; it < 6; ++it){
    sv = m ? next_sdf : 0.f;
    sv = (sv <= THRS) ? 0.f : sv;
    m = m && (sv > THRS);
    z = fmaf(sgn, sv, z);
    px = fmaf(z, dx, ox); py = fmaf(z, dy, oy); pz = fmaf(z, dz, oz);
    ((float*)(sm+PXB))[t] = px;
    ((float*)(sm+PYB))[t] = py;
    ((float*)(sm+PZB))[t] = pz;

    const int need = __syncthreads_or((int)m);   // barrier: points visible
    if (need){
      const float e = eval_block(sm, t);
      next_sdf = m ? e : 0.f;
    } else {
      next_sdf = 0.f;
    }

    bool fm = next_sdf < 0.f;
    float step = 0.5f;
    for (int fi = 0; fi < 3; ++fi){
      const int needf = __syncthreads_or((int)fm);
      if (needf){
        if (fm){
          z = fmaf(-step*sgn, sv, z);
          px = fmaf(z, dx, ox); py = fmaf(z, dy, oy); pz = fmaf(z, dz, oz);
          ((float*)(sm+PXB))[t] = px;
          ((float*)(sm+PYB))[t] = py;
          ((float*)(sm+PZB))[t] = pz;
        }
        const float f = eval_block(sm, t);
        if (fm) next_sdf = f;
        fm = next_sdf < 0.f;
      }
      step *= 0.5f;
    }

    // cross-channel coupling: adjacent thread holds the sibling channel
    const float zo = __shfl_xor(z, 1);
    const bool pair = c01 ? (zo < z) : (z < zo);
    m = m && pair;

    // all-dead fixed-point: remaining iterations are exact no-ops
    if (!__syncthreads_or((int)m)) break;
  }

  // final top-of-loop mask update
  sv = m ? next_sdf : 0.f;
  sv = (sv <= THRS) ? 0.f : sv;
  m = m && (sv > THRS);

  // outputs: points (2,N,3), z (2,N), mask (2,N) flat
  const size_t pb = (size_t)c01 * NRAYS * 3 + (size_t)ray * 3;
  out[pb+0] = px; out[pb+1] = py; out[pb+2] = pz;
  out[2*NRAYS*3 + (size_t)c01*NRAYS + ray] = z;
  out[2*NRAYS*3 + 2*NRAYS + (size_t)c01*NRAYS + ray] = m ? 1.f : 0.f;
}

extern "C" void kernel_launch(void* const* d_in, const int* in_sizes, int n_in,
                              void* d_out, int out_size, void* d_ws, size_t ws_size,
                              hipStream_t stream) {
  const float* rays_d = (const float*)d_in[0];
  const float* rays_o = (const float*)d_in[1];
  const float* W1 = (const float*)d_in[2];
  const float* b1 = (const float*)d_in[3];
  const float* W2 = (const float*)d_in[4];
  const float* b2 = (const float*)d_in[5];
  const float* W3 = (const float*)d_in[6];
  const float* b3 = (const float*)d_in[7];
  float* out = (float*)d_out;
  (void)d_ws; (void)ws_size;

  // 65536 ray-channels / 256 per block = 256 blocks = 1 per CU, single round
  trace_kernel<<<256, 256, 0, stream>>>(
      rays_d, rays_o, W1, b1, W2, b2, W3, b3, out);
}

// Round 7
// 32.877 us; speedup vs baseline: 9.0920x; 1.1561x over previous
//
#include <hip/hip_runtime.h>

#define NRAYS 32768
#define THRS  5e-5f

typedef float f32x4 __attribute__((ext_vector_type(4)));
typedef short s16x8 __attribute__((ext_vector_type(8)));

// ---- LDS byte map (105488 B total, 1 block/CU) ----
// W2 3-split bf16, B-fragment order: region(split s, coltile ct 0..7, kslice kb 0..3)
#define WB(s,ct,kb) ((((s)*8+(ct))*4+(kb))*1024)
#define T1B  98304   // float4[128] = (W1x,W1y,W1z,b1)
#define B2B  100352  // float[128]
#define W3B  100864  // float[128]
#define B3B  101376  // float (padded to 16)
#define PXB  101392  // float[256]
#define PYB  102416
#define PZB  103440
#define SDFB 104464  // float[256]
#define LDSZ 105488

// Cheap softplus: max(x,0) + ln2 * log2(1 + 2^(-|x|*log2e)).
__device__ __forceinline__ float softplus_f(float x){
  const float L2E = 1.44269504088896340f;
  const float LN2 = 0.69314718055994531f;
  float y = __builtin_amdgcn_exp2f(-fabsf(x) * L2E);
  float l = __builtin_amdgcn_logf(1.0f + y);      // log2(1+y)
  return fmaf(LN2, l, fmaxf(x, 0.0f));
}

__device__ __forceinline__ float bf16tof(unsigned short h){
  return __uint_as_float(((unsigned int)h) << 16);
}
// Truncation 3-way bf16 split: h = a0+a1+a2 + r, |r| <~ 2^-24|h|.
__device__ __forceinline__ void split3(float h, unsigned short& a0,
                                       unsigned short& a1, unsigned short& a2){
  a0 = (unsigned short)(__float_as_uint(h) >> 16);
  const float r1 = h - bf16tof(a0);
  a1 = (unsigned short)(__float_as_uint(r1) >> 16);
  const float r2 = r1 - bf16tof(a1);
  a2 = (unsigned short)(__float_as_uint(r2) >> 16);
}

// Batched M=256 MLP eval, 512 threads (8 waves). Wave w owns rows
// w*32..w*32+31 (2 m-tiles); A-fragments built directly in registers.
// Caller must have a barrier between point-writes and this call.
// Returns sdf for row t (valid for t<256).
__device__ __forceinline__ float eval_block(unsigned char* sm, int t){
  const int lane = t & 63;
  const int wave = t >> 6;          // 0..7
  const int l15  = lane & 15;
  const int lhi  = lane >> 4;

  // my 2 row-tiles' points (broadcast LDS reads)
  float prx[2], pry[2], prz[2];
#pragma unroll
  for (int mt = 0; mt < 2; ++mt){
    const int row = wave*32 + mt*16 + l15;
    prx[mt] = ((const float*)(sm+PXB))[row];
    pry[mt] = ((const float*)(sm+PYB))[row];
    prz[mt] = ((const float*)(sm+PZB))[row];
  }

  f32x4 acc[2][8];
#pragma unroll
  for (int mt = 0; mt < 2; ++mt)
#pragma unroll
    for (int ct = 0; ct < 8; ++ct){
      f32x4 zv = {0.f,0.f,0.f,0.f};
      acc[mt][ct] = zv;
    }

#pragma unroll
  for (int kb = 0; kb < 4; ++kb){
    // ---- layer 1 for this k-slice, 3-way bf16 trunc-split, A-frag order
    s16x8 A0[2], A1[2], A2[2];
#pragma unroll
    for (int u = 0; u < 8; ++u){
      const int k = kb*32 + lhi*8 + u;          // per-lane k
      const float4 t1 = ((const float4*)(sm+T1B))[k];
#pragma unroll
      for (int mt = 0; mt < 2; ++mt){
        const float pre = fmaf(prx[mt], t1.x,
                          fmaf(pry[mt], t1.y,
                          fmaf(prz[mt], t1.z, t1.w)));
        const float h = softplus_f(pre);
        unsigned short uh, um, ul;
        split3(h, uh, um, ul);
        A0[mt][u] = (short)uh; A1[mt][u] = (short)um; A2[mt][u] = (short)ul;
      }
    }
    // ---- layer 2: 6-product bf16x3 MFMA (err ~2^-24), all 8 col-tiles
#pragma unroll
    for (int ct = 0; ct < 8; ++ct){
      const s16x8 B0  = *(const s16x8*)(sm + WB(0,ct,kb) + lane*16);
      const s16x8 B1  = *(const s16x8*)(sm + WB(1,ct,kb) + lane*16);
      const s16x8 B2w = *(const s16x8*)(sm + WB(2,ct,kb) + lane*16);
#pragma unroll
      for (int mt = 0; mt < 2; ++mt){
        f32x4 a = acc[mt][ct];
        a = __builtin_amdgcn_mfma_f32_16x16x32_bf16(A0[mt], B0,  a, 0,0,0);
        a = __builtin_amdgcn_mfma_f32_16x16x32_bf16(A0[mt], B1,  a, 0,0,0);
        a = __builtin_amdgcn_mfma_f32_16x16x32_bf16(A1[mt], B0,  a, 0,0,0);
        a = __builtin_amdgcn_mfma_f32_16x16x32_bf16(A0[mt], B2w, a, 0,0,0);
        a = __builtin_amdgcn_mfma_f32_16x16x32_bf16(A1[mt], B1,  a, 0,0,0);
        a = __builtin_amdgcn_mfma_f32_16x16x32_bf16(A2[mt], B0,  a, 0,0,0);
        acc[mt][ct] = a;
      }
    }
  }

  // ---- layer 3: sdf[row] = sum_col sp(C+b2)*W3 (+b3 added at read)
  float b2v[8], w3v[8];
#pragma unroll
  for (int ct = 0; ct < 8; ++ct){
    const int col = ct*16 + l15;
    b2v[ct] = ((const float*)(sm+B2B))[col];
    w3v[ct] = ((const float*)(sm+W3B))[col];
  }
#pragma unroll
  for (int mt = 0; mt < 2; ++mt){
#pragma unroll
    for (int i = 0; i < 4; ++i){
      // C layout (m89-verified): row = wave*32 + mt*16 + lhi*4 + i, col = ct*16 + l15
      float v = 0.f;
#pragma unroll
      for (int ct = 0; ct < 8; ++ct)
        v = fmaf(softplus_f(acc[mt][ct][i] + b2v[ct]), w3v[ct], v);
      v += __shfl_xor(v, 1);
      v += __shfl_xor(v, 2);
      v += __shfl_xor(v, 4);
      v += __shfl_xor(v, 8);                     // reduce over 16 col-lanes
      if (l15 == 0)
        ((float*)(sm+SDFB))[wave*32 + mt*16 + lhi*4 + i] = v;
    }
  }
  __syncthreads();
  float r = 0.f;
  if (t < 256)
    r = ((const float*)(sm+SDFB))[t] + *((const float*)(sm+B3B));
  return r;
}

__global__ __launch_bounds__(512, 2)
void trace_kernel(const float* __restrict__ rays_d, const float* __restrict__ rays_o,
                  const float* __restrict__ W1, const float* __restrict__ b1,
                  const float* __restrict__ W2, const float* __restrict__ b2,
                  const float* __restrict__ W3, const float* __restrict__ b3,
                  float* __restrict__ out)
{
  __shared__ __align__(16) unsigned char sm[LDSZ];
  const int t = threadIdx.x;

  // ---- stage W2: 3-split bf16, B-fragment order, conflict-free b128 writes.
  for (int si = t; si < 2048; si += 512){
    const int k    = si & 127;
    const int joct = si >> 7;
    s16x8 vh, vm, vl;
#pragma unroll
    for (int jj = 0; jj < 8; ++jj){
      const float w = W2[(joct*8 + jj)*128 + k];   // coalesced over lanes (k)
      unsigned short uh, um, ul;
      split3(w, uh, um, ul);
      vh[jj] = (short)uh; vm[jj] = (short)um; vl[jj] = (short)ul;
    }
    const int ct = k >> 4, kb = joct >> 2;
    const int slot = ((joct & 3)*16 + (k & 15))*16;
    *(s16x8*)(sm + WB(0,ct,kb) + slot) = vh;
    *(s16x8*)(sm + WB(1,ct,kb) + slot) = vm;
    *(s16x8*)(sm + WB(2,ct,kb) + slot) = vl;
  }
  if (t < 128){
    ((float4*)(sm+T1B))[t] = make_float4(W1[t], W1[128+t], W1[256+t], b1[t]);
    ((float*)(sm+B2B))[t] = b2[t];
    ((float*)(sm+W3B))[t] = W3[t];
  }
  if (t == 0) *((float*)(sm+B3B)) = b3[0];

  // ---- per-channel trace state: threads 0..255 own channels
  const bool own = (t < 256);
  const int chan = blockIdx.x * 256 + (t & 255);
  const int ray  = chan >> 1;
  const int c01  = chan & 1;
  const float sgn = c01 ? -1.0f : 1.0f;

  float dx=0, dy=0, dz=0, ox=0, oy=0, oz=0;
  if (own){
    dx = rays_d[ray*3+0]; dy = rays_d[ray*3+1]; dz = rays_d[ray*3+2];
    ox = rays_o[ray*3+0]; oy = rays_o[ray*3+1]; oz = rays_o[ray*3+2];
    ((float*)(sm+PXB))[t] = ox;
    ((float*)(sm+PYB))[t] = oy;
    ((float*)(sm+PZB))[t] = oz;
  }
  __syncthreads();

  float next_sdf = eval_block(sm, t);   // sdf at origins
  float z = 0.f, sv = 0.f;
  float px = ox, py = oy, pz = oz;
  bool m = own;

  for (int it = 0; it < 6; ++it){
    sv = m ? next_sdf : 0.f;
    sv = (sv <= THRS) ? 0.f : sv;
    m = m && (sv > THRS);
    z = fmaf(sgn, sv, z);
    px = fmaf(z, dx, ox); py = fmaf(z, dy, oy); pz = fmaf(z, dz, oz);
    if (own){
      ((float*)(sm+PXB))[t] = px;
      ((float*)(sm+PYB))[t] = py;
      ((float*)(sm+PZB))[t] = pz;
    }

    const int need = __syncthreads_or((int)m);   // barrier: points visible
    if (need){
      const float e = eval_block(sm, t);
      next_sdf = m ? e : 0.f;
    } else {
      next_sdf = 0.f;
    }

    bool fm = own && (next_sdf < 0.f);
    float step = 0.5f;
    for (int fi = 0; fi < 3; ++fi){
      const int needf = __syncthreads_or((int)fm);
      if (needf){
        if (fm){
          z = fmaf(-step*sgn, sv, z);
          px = fmaf(z, dx, ox); py = fmaf(z, dy, oy); pz = fmaf(z, dz, oz);
          ((float*)(sm+PXB))[t] = px;
          ((float*)(sm+PYB))[t] = py;
          ((float*)(sm+PZB))[t] = pz;
        }
        const float f = eval_block(sm, t);
        if (fm) next_sdf = f;
        fm = own && (next_sdf < 0.f);
      }
      step *= 0.5f;
    }

    // cross-channel coupling: adjacent thread holds the sibling channel
    const float zo = __shfl_xor(z, 1);
    const bool pair = c01 ? (zo < z) : (z < zo);
    m = m && pair;

    // all-dead fixed-point: remaining iterations are exact no-ops
    if (!__syncthreads_or((int)m)) break;
  }

  if (own){
    // final top-of-loop mask update
    sv = m ? next_sdf : 0.f;
    sv = (sv <= THRS) ? 0.f : sv;
    m = m && (sv > THRS);

    // outputs: points (2,N,3), z (2,N), mask (2,N) flat
    const size_t pb = (size_t)c01 * NRAYS * 3 + (size_t)ray * 3;
    out[pb+0] = px; out[pb+1] = py; out[pb+2] = pz;
    out[2*NRAYS*3 + (size_t)c01*NRAYS + ray] = z;
    out[2*NRAYS*3 + 2*NRAYS + (size_t)c01*NRAYS + ray] = m ? 1.f : 0.f;
  }
}

extern "C" void kernel_launch(void* const* d_in, const int* in_sizes, int n_in,
                              void* d_out, int out_size, void* d_ws, size_t ws_size,
                              hipStream_t stream) {
  const float* rays_d = (const float*)d_in[0];
  const float* rays_o = (const float*)d_in[1];
  const float* W1 = (const float*)d_in[2];
  const float* b1 = (const float*)d_in[3];
  const float* W2 = (const float*)d_in[4];
  const float* b2 = (const float*)d_in[5];
  const float* W3 = (const float*)d_in[6];
  const float* b3 = (const float*)d_in[7];
  float* out = (float*)d_out;
  (void)d_ws; (void)ws_size;

  // 256 blocks x 512 threads; each block owns 256 ray-channels (1 block/CU)
  trace_kernel<<<256, 512, 0, stream>>>(
      rays_d, rays_o, W1, b1, W2, b2, W3, b3, out);
}

// Round 8
// 28.887 us; speedup vs baseline: 10.3477x; 1.1381x over previous
//
#include <hip/hip_runtime.h>

#define NRAYS 32768
#define THRS  5e-5f

typedef float f32x4 __attribute__((ext_vector_type(4)));
typedef short s16x8 __attribute__((ext_vector_type(8)));

// ---- LDS byte map (105520 B total, 1 block/CU) ----
// W2 3-split bf16, B-fragment order: region(split s, coltile ct 0..7, kslice kb 0..3)
#define WB(s,ct,kb) ((((s)*8+(ct))*4+(kb))*1024)
#define T1B  98304   // float4[128] = (W1x,W1y,W1z,b1)
#define B2B  100352  // float[128]
#define W3B  100864  // float[128]
#define B3B  101376  // float (padded to 16)
#define PXB  101392  // float[256] compacted point x
#define PYB  102416
#define PZB  103440
#define SDFB 104464  // float[256]
#define CNTB 105488  // int[8] per-wave active counts
#define LDSZ 105520

// Cheap softplus: max(x,0) + ln2 * log2(1 + 2^(-|x|*log2e)).
__device__ __forceinline__ float softplus_f(float x){
  const float L2E = 1.44269504088896340f;
  const float LN2 = 0.69314718055994531f;
  float y = __builtin_amdgcn_exp2f(-fabsf(x) * L2E);
  float l = __builtin_amdgcn_logf(1.0f + y);      // log2(1+y)
  return fmaf(LN2, l, fmaxf(x, 0.0f));
}

__device__ __forceinline__ float bf16tof(unsigned short h){
  return __uint_as_float(((unsigned int)h) << 16);
}
// Truncation 3-way bf16 split: exact for fp32 (3x8 = 24 mantissa bits).
__device__ __forceinline__ void split3(float h, unsigned short& a0,
                                       unsigned short& a1, unsigned short& a2){
  a0 = (unsigned short)(__float_as_uint(h) >> 16);
  const float r1 = h - bf16tof(a0);
  a1 = (unsigned short)(__float_as_uint(r1) >> 16);
  const float r2 = r1 - bf16tof(a1);
  a2 = (unsigned short)(__float_as_uint(r2) >> 16);
}

// Batched MLP eval over compacted rows 0..nw*32-1. Waves >= nw skip all
// work (B-read traffic scales with nw). Ends with a barrier (SDFB ready).
__device__ __forceinline__ void eval_blockN(unsigned char* sm, int t, int nw){
  const int lane = t & 63;
  const int wave = t >> 6;          // 0..7
  const int l15  = lane & 15;
  const int lhi  = lane >> 4;

  if (wave < nw){
    // my 2 row-tiles' points (broadcast LDS reads)
    float prx[2], pry[2], prz[2];
#pragma unroll
    for (int mt = 0; mt < 2; ++mt){
      const int row = wave*32 + mt*16 + l15;
      prx[mt] = ((const float*)(sm+PXB))[row];
      pry[mt] = ((const float*)(sm+PYB))[row];
      prz[mt] = ((const float*)(sm+PZB))[row];
    }

    f32x4 acc[2][8];
#pragma unroll
    for (int mt = 0; mt < 2; ++mt)
#pragma unroll
      for (int ct = 0; ct < 8; ++ct){
        f32x4 zv = {0.f,0.f,0.f,0.f};
        acc[mt][ct] = zv;
      }

#pragma unroll
    for (int kb = 0; kb < 4; ++kb){
      // layer 1 for this k-slice, 3-way bf16 trunc-split, A-frag order
      s16x8 A0[2], A1[2], A2[2];
#pragma unroll
      for (int u = 0; u < 8; ++u){
        const int k = kb*32 + lhi*8 + u;          // per-lane k
        const float4 t1 = ((const float4*)(sm+T1B))[k];
#pragma unroll
        for (int mt = 0; mt < 2; ++mt){
          const float pre = fmaf(prx[mt], t1.x,
                            fmaf(pry[mt], t1.y,
                            fmaf(prz[mt], t1.z, t1.w)));
          const float h = softplus_f(pre);
          unsigned short uh, um, ul;
          split3(h, uh, um, ul);
          A0[mt][u] = (short)uh; A1[mt][u] = (short)um; A2[mt][u] = (short)ul;
        }
      }
      // layer 2: 6-product bf16x3 MFMA (fp32-exact dot), all 8 col-tiles
#pragma unroll
      for (int ct = 0; ct < 8; ++ct){
        const s16x8 B0  = *(const s16x8*)(sm + WB(0,ct,kb) + lane*16);
        const s16x8 B1  = *(const s16x8*)(sm + WB(1,ct,kb) + lane*16);
        const s16x8 B2w = *(const s16x8*)(sm + WB(2,ct,kb) + lane*16);
#pragma unroll
        for (int mt = 0; mt < 2; ++mt){
          f32x4 a = acc[mt][ct];
          a = __builtin_amdgcn_mfma_f32_16x16x32_bf16(A0[mt], B0,  a, 0,0,0);
          a = __builtin_amdgcn_mfma_f32_16x16x32_bf16(A0[mt], B1,  a, 0,0,0);
          a = __builtin_amdgcn_mfma_f32_16x16x32_bf16(A1[mt], B0,  a, 0,0,0);
          a = __builtin_amdgcn_mfma_f32_16x16x32_bf16(A0[mt], B2w, a, 0,0,0);
          a = __builtin_amdgcn_mfma_f32_16x16x32_bf16(A1[mt], B1,  a, 0,0,0);
          a = __builtin_amdgcn_mfma_f32_16x16x32_bf16(A2[mt], B0,  a, 0,0,0);
          acc[mt][ct] = a;
        }
      }
    }

    // layer 3: sdf[row] = sum_col sp(C+b2)*W3 (+b3 added at read)
    float b2v[8], w3v[8];
#pragma unroll
    for (int ct = 0; ct < 8; ++ct){
      const int col = ct*16 + l15;
      b2v[ct] = ((const float*)(sm+B2B))[col];
      w3v[ct] = ((const float*)(sm+W3B))[col];
    }
#pragma unroll
    for (int mt = 0; mt < 2; ++mt){
#pragma unroll
      for (int i = 0; i < 4; ++i){
        // C layout (m89-verified): row = wave*32+mt*16+lhi*4+i, col = ct*16+l15
        float v = 0.f;
#pragma unroll
        for (int ct = 0; ct < 8; ++ct)
          v = fmaf(softplus_f(acc[mt][ct][i] + b2v[ct]), w3v[ct], v);
        v += __shfl_xor(v, 1);
        v += __shfl_xor(v, 2);
        v += __shfl_xor(v, 4);
        v += __shfl_xor(v, 8);                   // reduce over 16 col-lanes
        if (l15 == 0)
          ((float*)(sm+SDFB))[wave*32 + mt*16 + lhi*4 + i] = v;
      }
    }
  }
  __syncthreads();                               // SDFB ready
}

// Ballot-scan compaction: returns block-total active count; slot = compact
// row index for this thread's channel (valid when f). One barrier inside.
__device__ __forceinline__ int compact_count(unsigned char* sm, int t, bool f,
                                             int& slot){
  const int lane = t & 63, wave = t >> 6;
  const unsigned long long bal = __ballot(f);
  if (lane == 0) ((int*)(sm+CNTB))[wave] = __popcll(bal);
  __syncthreads();
  const int* wc = (const int*)(sm+CNTB);
  const int c0 = wc[0], c1 = wc[1], c2 = wc[2], c3 = wc[3];
  int base = 0;
  if (wave > 0) base += c0;
  if (wave > 1) base += c1;
  if (wave > 2) base += c2;                      // waves>=4 never use slot
  slot = base + __popcll(bal & ((1ULL << lane) - 1ULL));
  return c0 + c1 + c2 + c3;                      // owners live in waves 0..3
}

// Compact + eval + gather. Returns SDF for flagged threads, prev otherwise.
// Uniform control flow; 2-3 barriers total.
__device__ __forceinline__ float do_eval(unsigned char* sm, int t, bool flag,
                                         float px, float py, float pz,
                                         float prev){
  int slot;
  const int cnt = compact_count(sm, t, flag, slot);
  if (cnt == 0) return prev;                     // block-uniform
  if (flag){
    ((float*)(sm+PXB))[slot] = px;
    ((float*)(sm+PYB))[slot] = py;
    ((float*)(sm+PZB))[slot] = pz;
  }
  __syncthreads();                               // points visible before reads
  eval_blockN(sm, t, (cnt + 31) >> 5);
  float r = prev;
  if (flag)
    r = ((const float*)(sm+SDFB))[slot] + *((const float*)(sm+B3B));
  return r;
}

__global__ __launch_bounds__(512, 2)
void trace_kernel(const float* __restrict__ rays_d, const float* __restrict__ rays_o,
                  const float* __restrict__ W1, const float* __restrict__ b1,
                  const float* __restrict__ W2, const float* __restrict__ b2,
                  const float* __restrict__ W3, const float* __restrict__ b3,
                  float* __restrict__ out)
{
  __shared__ __align__(16) unsigned char sm[LDSZ];
  const int t = threadIdx.x;

  // ---- stage W2: 3-split bf16, B-fragment order, conflict-free b128 writes.
  for (int si = t; si < 2048; si += 512){
    const int k    = si & 127;
    const int joct = si >> 7;
    s16x8 vh, vm, vl;
#pragma unroll
    for (int jj = 0; jj < 8; ++jj){
      const float w = W2[(joct*8 + jj)*128 + k];   // coalesced over lanes (k)
      unsigned short uh, um, ul;
      split3(w, uh, um, ul);
      vh[jj] = (short)uh; vm[jj] = (short)um; vl[jj] = (short)ul;
    }
    const int ct = k >> 4, kb = joct >> 2;
    const int slot = ((joct & 3)*16 + (k & 15))*16;
    *(s16x8*)(sm + WB(0,ct,kb) + slot) = vh;
    *(s16x8*)(sm + WB(1,ct,kb) + slot) = vm;
    *(s16x8*)(sm + WB(2,ct,kb) + slot) = vl;
  }
  if (t < 128){
    ((float4*)(sm+T1B))[t] = make_float4(W1[t], W1[128+t], W1[256+t], b1[t]);
    ((float*)(sm+B2B))[t] = b2[t];
    ((float*)(sm+W3B))[t] = W3[t];
  }
  if (t == 0) *((float*)(sm+B3B)) = b3[0];
  // (staging-writes ordered before first eval by compact_count's barrier)

  // ---- per-channel trace state: threads 0..255 own channels
  const bool own = (t < 256);
  const int chan = blockIdx.x * 256 + (t & 255);
  const int ray  = chan >> 1;
  const int c01  = chan & 1;
  const float sgn = c01 ? -1.0f : 1.0f;

  float dx=0, dy=0, dz=0, ox=0, oy=0, oz=0;
  if (own){
    dx = rays_d[ray*3+0]; dy = rays_d[ray*3+1]; dz = rays_d[ray*3+2];
    ox = rays_o[ray*3+0]; oy = rays_o[ray*3+1]; oz = rays_o[ray*3+2];
  }

  // initial eval at origins (all 256 channels; slot == t)
  float next_sdf = do_eval(sm, t, own, ox, oy, oz, 0.f);

  float z = 0.f, sv = 0.f;
  float px = ox, py = oy, pz = oz;
  bool m = own;

  for (int it = 0; it < 6; ++it){
    sv = m ? next_sdf : 0.f;
    sv = (sv <= THRS) ? 0.f : sv;
    m = m && (sv > THRS);
    z = fmaf(sgn, sv, z);
    px = fmaf(z, dx, ox); py = fmaf(z, dy, oy); pz = fmaf(z, dz, oz);

    // step eval: only channels still marching
    next_sdf = do_eval(sm, t, m, px, py, pz, 0.f);

    bool fm = own && (next_sdf < 0.f);
    float step = 0.5f;
    for (int fi = 0; fi < 3; ++fi){
      if (fm){
        z = fmaf(-step*sgn, sv, z);
        px = fmaf(z, dx, ox); py = fmaf(z, dy, oy); pz = fmaf(z, dz, oz);
      }
      // fix eval: only overshooting channels (compacted)
      next_sdf = do_eval(sm, t, fm, px, py, pz, next_sdf);
      fm = own && (next_sdf < 0.f);
      step *= 0.5f;
    }

    // cross-channel coupling: adjacent thread holds the sibling channel
    const float zo = __shfl_xor(z, 1);
    const bool pair = c01 ? (zo < z) : (z < zo);
    m = m && pair;

    // all-dead fixed-point: remaining iterations are exact no-ops
    if (!__syncthreads_or((int)m)) break;
  }

  if (own){
    // final top-of-loop mask update
    sv = m ? next_sdf : 0.f;
    sv = (sv <= THRS) ? 0.f : sv;
    m = m && (sv > THRS);

    // outputs: points (2,N,3), z (2,N), mask (2,N) flat
    const size_t pb = (size_t)c01 * NRAYS * 3 + (size_t)ray * 3;
    out[pb+0] = px; out[pb+1] = py; out[pb+2] = pz;
    out[2*NRAYS*3 + (size_t)c01*NRAYS + ray] = z;
    out[2*NRAYS*3 + 2*NRAYS + (size_t)c01*NRAYS + ray] = m ? 1.f : 0.f;
  }
}

extern "C" void kernel_launch(void* const* d_in, const int* in_sizes, int n_in,
                              void* d_out, int out_size, void* d_ws, size_t ws_size,
                              hipStream_t stream) {
  const float* rays_d = (const float*)d_in[0];
  const float* rays_o = (const float*)d_in[1];
  const float* W1 = (const float*)d_in[2];
  const float* b1 = (const float*)d_in[3];
  const float* W2 = (const float*)d_in[4];
  const float* b2 = (const float*)d_in[5];
  const float* W3 = (const float*)d_in[6];
  const float* b3 = (const float*)d_in[7];
  float* out = (float*)d_out;
  (void)d_ws; (void)ws_size;

  // 256 blocks x 512 threads; each block owns 256 ray-channels (1 block/CU)
  trace_kernel<<<256, 512, 0, stream>>>(
      rays_d, rays_o, W1, b1, W2, b2, W3, b3, out);
}

// Round 10
// 25.467 us; speedup vs baseline: 11.7371x; 1.1343x over previous
//
#include <hip/hip_runtime.h>

#define NRAYS 32768
#define THRS  5e-5f

typedef float f32x4 __attribute__((ext_vector_type(4)));
typedef short s16x8 __attribute__((ext_vector_type(8)));

// ---- LDS byte map (105520 B total, 1 block/CU) ----
// W2 3-split bf16, B-fragment order: region(split s, coltile ct 0..7, kslice kb 0..3)
#define WB(s,ct,kb) ((((s)*8+(ct))*4+(kb))*1024)
#define T1B  98304   // float4[128] = (W1x,W1y,W1z,b1)
#define B2B  100352  // float[128]
#define W3B  100864  // float[128]
#define B3B  101376  // float (padded to 16)
#define PXB  101392  // float[256] compacted point x
#define PYB  102416
#define PZB  103440
#define SDFB 104464  // float[256]
#define CNTB 105488  // int[8] per-wave active counts
#define LDSZ 105520

// Cheap softplus: max(x,0) + ln2 * log2(1 + 2^(-|x|*log2e)).
__device__ __forceinline__ float softplus_f(float x){
  const float L2E = 1.44269504088896340f;
  const float LN2 = 0.69314718055994531f;
  float y = __builtin_amdgcn_exp2f(-fabsf(x) * L2E);
  float l = __builtin_amdgcn_logf(1.0f + y);      // log2(1+y)
  return fmaf(LN2, l, fmaxf(x, 0.0f));
}

__device__ __forceinline__ float bf16tof(unsigned short h){
  return __uint_as_float(((unsigned int)h) << 16);
}
// Truncation 3-way bf16 split: exact for fp32 (3x8 = 24 mantissa bits).
__device__ __forceinline__ void split3(float h, unsigned short& a0,
                                       unsigned short& a1, unsigned short& a2){
  a0 = (unsigned short)(__float_as_uint(h) >> 16);
  const float r1 = h - bf16tof(a0);
  a1 = (unsigned short)(__float_as_uint(r1) >> 16);
  const float r2 = r1 - bf16tof(a1);
  a2 = (unsigned short)(__float_as_uint(r2) >> 16);
}

// Batched MLP eval over compacted rows 0..nw*32-1. Waves >= nw skip all
// work (B-read traffic scales with nw). Ends with a barrier (SDFB ready).
__device__ __forceinline__ void eval_blockN(unsigned char* sm, int t, int nw){
  const int lane = t & 63;
  const int wave = t >> 6;          // 0..7
  const int l15  = lane & 15;
  const int lhi  = lane >> 4;

  if (wave < nw){
    // my 2 row-tiles' points (broadcast LDS reads)
    float prx[2], pry[2], prz[2];
#pragma unroll
    for (int mt = 0; mt < 2; ++mt){
      const int row = wave*32 + mt*16 + l15;
      prx[mt] = ((const float*)(sm+PXB))[row];
      pry[mt] = ((const float*)(sm+PYB))[row];
      prz[mt] = ((const float*)(sm+PZB))[row];
    }

    f32x4 acc[2][8];
#pragma unroll
    for (int mt = 0; mt < 2; ++mt)
#pragma unroll
      for (int ct = 0; ct < 8; ++ct){
        f32x4 zv = {0.f,0.f,0.f,0.f};
        acc[mt][ct] = zv;
      }

#pragma unroll
    for (int kb = 0; kb < 4; ++kb){
      // layer 1 for this k-slice, 3-way bf16 trunc-split, A-frag order
      s16x8 A0[2], A1[2], A2[2];
#pragma unroll
      for (int u = 0; u < 8; ++u){
        const int k = kb*32 + lhi*8 + u;          // per-lane k
        const float4 t1 = ((const float4*)(sm+T1B))[k];
#pragma unroll
        for (int mt = 0; mt < 2; ++mt){
          const float pre = fmaf(prx[mt], t1.x,
                            fmaf(pry[mt], t1.y,
                            fmaf(prz[mt], t1.z, t1.w)));
          const float h = softplus_f(pre);
          unsigned short uh, um, ul;
          split3(h, uh, um, ul);
          A0[mt][u] = (short)uh; A1[mt][u] = (short)um; A2[mt][u] = (short)ul;
        }
      }
      // layer 2: 6-product bf16x3 MFMA (fp32-exact dot), all 8 col-tiles
#pragma unroll
      for (int ct = 0; ct < 8; ++ct){
        const s16x8 B0  = *(const s16x8*)(sm + WB(0,ct,kb) + lane*16);
        const s16x8 B1  = *(const s16x8*)(sm + WB(1,ct,kb) + lane*16);
        const s16x8 B2w = *(const s16x8*)(sm + WB(2,ct,kb) + lane*16);
#pragma unroll
        for (int mt = 0; mt < 2; ++mt){
          f32x4 a = acc[mt][ct];
          a = __builtin_amdgcn_mfma_f32_16x16x32_bf16(A0[mt], B0,  a, 0,0,0);
          a = __builtin_amdgcn_mfma_f32_16x16x32_bf16(A0[mt], B1,  a, 0,0,0);
          a = __builtin_amdgcn_mfma_f32_16x16x32_bf16(A1[mt], B0,  a, 0,0,0);
          a = __builtin_amdgcn_mfma_f32_16x16x32_bf16(A0[mt], B2w, a, 0,0,0);
          a = __builtin_amdgcn_mfma_f32_16x16x32_bf16(A1[mt], B1,  a, 0,0,0);
          a = __builtin_amdgcn_mfma_f32_16x16x32_bf16(A2[mt], B0,  a, 0,0,0);
          acc[mt][ct] = a;
        }
      }
    }

    // layer 3: sdf[row] = sum_col sp(C+b2)*W3 (+b3 added at read)
    float b2v[8], w3v[8];
#pragma unroll
    for (int ct = 0; ct < 8; ++ct){
      const int col = ct*16 + l15;
      b2v[ct] = ((const float*)(sm+B2B))[col];
      w3v[ct] = ((const float*)(sm+W3B))[col];
    }
#pragma unroll
    for (int mt = 0; mt < 2; ++mt){
#pragma unroll
      for (int i = 0; i < 4; ++i){
        // C layout (m89-verified): row = wave*32+mt*16+lhi*4+i, col = ct*16+l15
        float v = 0.f;
#pragma unroll
        for (int ct = 0; ct < 8; ++ct)
          v = fmaf(softplus_f(acc[mt][ct][i] + b2v[ct]), w3v[ct], v);
        v += __shfl_xor(v, 1);
        v += __shfl_xor(v, 2);
        v += __shfl_xor(v, 4);
        v += __shfl_xor(v, 8);                   // reduce over 16 col-lanes
        if (l15 == 0)
          ((float*)(sm+SDFB))[wave*32 + mt*16 + lhi*4 + i] = v;
      }
    }
  }
  __syncthreads();                               // SDFB ready
}

// Ballot-scan compaction: returns block-total active count; slot = compact
// row index for this thread's channel (valid when f). One barrier inside.
__device__ __forceinline__ int compact_count(unsigned char* sm, int t, bool f,
                                             int& slot){
  const int lane = t & 63, wave = t >> 6;
  const unsigned long long bal = __ballot(f);
  if (lane == 0) ((int*)(sm+CNTB))[wave] = __popcll(bal);
  __syncthreads();
  const int* wc = (const int*)(sm+CNTB);
  const int c0 = wc[0], c1 = wc[1], c2 = wc[2], c3 = wc[3];
  int base = 0;
  if (wave > 0) base += c0;
  if (wave > 1) base += c1;
  if (wave > 2) base += c2;                      // waves>=4 never use slot
  slot = base + __popcll(bal & ((1ULL << lane) - 1ULL));
  return c0 + c1 + c2 + c3;                      // owners live in waves 0..3
}

// Compact + eval + gather. Returns SDF for flagged threads, prev otherwise.
// Uniform control flow; 2-3 barriers total.
__device__ __forceinline__ float do_eval(unsigned char* sm, int t, bool flag,
                                         float px, float py, float pz,
                                         float prev){
  int slot;
  const int cnt = compact_count(sm, t, flag, slot);
  if (cnt == 0) return prev;                     // block-uniform
  if (flag){
    ((float*)(sm+PXB))[slot] = px;
    ((float*)(sm+PYB))[slot] = py;
    ((float*)(sm+PZB))[slot] = pz;
  }
  __syncthreads();                               // points visible before reads
  eval_blockN(sm, t, (cnt + 31) >> 5);
  float r = prev;
  if (flag)
    r = ((const float*)(sm+SDFB))[slot] + *((const float*)(sm+B3B));
  return r;
}

__global__ __launch_bounds__(512, 2)
void trace_kernel(const float* __restrict__ rays_d, const float* __restrict__ rays_o,
                  const float* __restrict__ W1, const float* __restrict__ b1,
                  const float* __restrict__ W2, const float* __restrict__ b2,
                  const float* __restrict__ W3, const float* __restrict__ b3,
                  float* __restrict__ out)
{
  __shared__ __align__(16) unsigned char sm[LDSZ];
  const int t = threadIdx.x;

  // ---- stage W2: 3-split bf16, B-fragment order, conflict-free b128 writes.
  for (int si = t; si < 2048; si += 512){
    const int k    = si & 127;
    const int joct = si >> 7;
    s16x8 vh, vm, vl;
#pragma unroll
    for (int jj = 0; jj < 8; ++jj){
      const float w = W2[(joct*8 + jj)*128 + k];   // coalesced over lanes (k)
      unsigned short uh, um, ul;
      split3(w, uh, um, ul);
      vh[jj] = (short)uh; vm[jj] = (short)um; vl[jj] = (short)ul;
    }
    const int ct = k >> 4, kb = joct >> 2;
    const int slot = ((joct & 3)*16 + (k & 15))*16;
    *(s16x8*)(sm + WB(0,ct,kb) + slot) = vh;
    *(s16x8*)(sm + WB(1,ct,kb) + slot) = vm;
    *(s16x8*)(sm + WB(2,ct,kb) + slot) = vl;
  }
  if (t < 128){
    ((float4*)(sm+T1B))[t] = make_float4(W1[t], W1[128+t], W1[256+t], b1[t]);
    ((float*)(sm+B2B))[t] = b2[t];
    ((float*)(sm+W3B))[t] = W3[t];
  }
  if (t == 0) *((float*)(sm+B3B)) = b3[0];
  // (staging-writes ordered before first eval by compact_count's barrier)

  // ---- per-channel trace state: threads 0..255 own channels
  const bool own = (t < 256);
  const int chan = blockIdx.x * 256 + (t & 255);
  const int ray  = chan >> 1;
  const int c01  = chan & 1;
  const float sgn = c01 ? -1.0f : 1.0f;

  float dx=0, dy=0, dz=0, ox=0, oy=0, oz=0;
  if (own){
    dx = rays_d[ray*3+0]; dy = rays_d[ray*3+1]; dz = rays_d[ray*3+2];
    ox = rays_o[ray*3+0]; oy = rays_o[ray*3+1]; oz = rays_o[ray*3+2];
  }

  // initial eval at origins: both channels share the SAME point (z=0), so
  // only even channels (c01==0) evaluate -> 128 rows = 4 waves; odd channels
  // take the sibling's value via shfl. NOTE: the shfl MUST be executed by
  // all lanes (ds_bpermute from an exec-masked-off lane is undefined) --
  // keep it as an unconditional statement, never inside the ternary.
  const float e0  = do_eval(sm, t, own && (c01 == 0), ox, oy, oz, 0.f);
  const float e0s = __shfl_xor(e0, 1);           // unconditional, all lanes
  float next_sdf = c01 ? e0s : e0;

  float z = 0.f, sv = 0.f;
  float px = ox, py = oy, pz = oz;
  bool m = own;

  for (int it = 0; it < 6; ++it){
    sv = m ? next_sdf : 0.f;
    sv = (sv <= THRS) ? 0.f : sv;
    m = m && (sv > THRS);
    z = fmaf(sgn, sv, z);
    px = fmaf(z, dx, ox); py = fmaf(z, dy, oy); pz = fmaf(z, dz, oz);

    // step eval: only channels still marching
    next_sdf = do_eval(sm, t, m, px, py, pz, 0.f);

    bool fm = own && (next_sdf < 0.f);
    float step = 0.5f;
    for (int fi = 0; fi < 3; ++fi){
      if (fm){
        z = fmaf(-step*sgn, sv, z);
        px = fmaf(z, dx, ox); py = fmaf(z, dy, oy); pz = fmaf(z, dz, oz);
      }
      // fix eval: only overshooting channels (compacted)
      next_sdf = do_eval(sm, t, fm, px, py, pz, next_sdf);
      fm = own && (next_sdf < 0.f);
      step *= 0.5f;
    }

    // cross-channel coupling: adjacent thread holds the sibling channel
    const float zo = __shfl_xor(z, 1);             // unconditional
    const bool pair = c01 ? (zo < z) : (z < zo);
    m = m && pair;

    // all-dead fixed-point: remaining iterations are exact no-ops
    if (!__syncthreads_or((int)m)) break;
  }

  if (own){
    // final top-of-loop mask update
    sv = m ? next_sdf : 0.f;
    sv = (sv <= THRS) ? 0.f : sv;
    m = m && (sv > THRS);

    // outputs: points (2,N,3), z (2,N), mask (2,N) flat
    const size_t pb = (size_t)c01 * NRAYS * 3 + (size_t)ray * 3;
    out[pb+0] = px; out[pb+1] = py; out[pb+2] = pz;
    out[2*NRAYS*3 + (size_t)c01*NRAYS + ray] = z;
    out[2*NRAYS*3 + 2*NRAYS + (size_t)c01*NRAYS + ray] = m ? 1.f : 0.f;
  }
}

extern "C" void kernel_launch(void* const* d_in, const int* in_sizes, int n_in,
                              void* d_out, int out_size, void* d_ws, size_t ws_size,
                              hipStream_t stream) {
  const float* rays_d = (const float*)d_in[0];
  const float* rays_o = (const float*)d_in[1];
  const float* W1 = (const float*)d_in[2];
  const float* b1 = (const float*)d_in[3];
  const float* W2 = (const float*)d_in[4];
  const float* b2 = (const float*)d_in[5];
  const float* W3 = (const float*)d_in[6];
  const float* b3 = (const float*)d_in[7];
  float* out = (float*)d_out;
  (void)d_ws; (void)ws_size;

  // 256 blocks x 512 threads; each block owns 256 ray-channels (1 block/CU)
  trace_kernel<<<256, 512, 0, stream>>>(
      rays_d, rays_o, W1, b1, W2, b2, W3, b3, out);
}

// Round 11
// 25.260 us; speedup vs baseline: 11.8335x; 1.0082x over previous
//
#include <hip/hip_runtime.h>

#define NRAYS 32768
#define THRS  5e-5f

typedef float f32x4 __attribute__((ext_vector_type(4)));
typedef short s16x8 __attribute__((ext_vector_type(8)));

// ---- LDS byte map (105616 B total, 1 block/CU) ----
// W2 3-split bf16, B-fragment order: region(split s, coltile ct 0..7, kslice kb 0..3)
#define WB(s,ct,kb) ((((s)*8+(ct))*4+(kb))*1024)
#define T1B  98304   // float4[128] = (W1x,W1y,W1z,b1)
#define B2B  100352  // float[128]
#define W3B  100864  // float[128]
#define B3B  101376  // float (padded to 16)
#define PXB  101392  // float[256] compacted point x
#define PYB  102416
#define PZB  103440
#define SDFB 104464  // float[256]
#define CNTB 105488  // int[32] rotating compaction counters (zeroed once)
#define LDSZ 105616

// Cheap softplus: max(x,0) + ln2 * log2(1 + 2^(-|x|*log2e)).
__device__ __forceinline__ float softplus_f(float x){
  const float L2E = 1.44269504088896340f;
  const float LN2 = 0.69314718055994531f;
  float y = __builtin_amdgcn_exp2f(-fabsf(x) * L2E);
  float l = __builtin_amdgcn_logf(1.0f + y);      // log2(1+y)
  return fmaf(LN2, l, fmaxf(x, 0.0f));
}

__device__ __forceinline__ float bf16tof(unsigned short h){
  return __uint_as_float(((unsigned int)h) << 16);
}
// Truncation 3-way bf16 split: exact for fp32 (3x8 = 24 mantissa bits).
__device__ __forceinline__ void split3(float h, unsigned short& a0,
                                       unsigned short& a1, unsigned short& a2){
  a0 = (unsigned short)(__float_as_uint(h) >> 16);
  const float r1 = h - bf16tof(a0);
  a1 = (unsigned short)(__float_as_uint(r1) >> 16);
  const float r2 = r1 - bf16tof(a1);
  a2 = (unsigned short)(__float_as_uint(r2) >> 16);
}

// Batched MLP eval over compacted rows 0..nw*32-1. Waves >= nw skip all
// work (B-read traffic scales with nw). Ends with a barrier (SDFB ready).
__device__ __forceinline__ void eval_blockN(unsigned char* sm, int t, int nw){
  const int lane = t & 63;
  const int wave = t >> 6;          // 0..7
  const int l15  = lane & 15;
  const int lhi  = lane >> 4;

  if (wave < nw){
    // my 2 row-tiles' points (broadcast LDS reads)
    float prx[2], pry[2], prz[2];
#pragma unroll
    for (int mt = 0; mt < 2; ++mt){
      const int row = wave*32 + mt*16 + l15;
      prx[mt] = ((const float*)(sm+PXB))[row];
      pry[mt] = ((const float*)(sm+PYB))[row];
      prz[mt] = ((const float*)(sm+PZB))[row];
    }

    f32x4 acc[2][8];
#pragma unroll
    for (int mt = 0; mt < 2; ++mt)
#pragma unroll
      for (int ct = 0; ct < 8; ++ct){
        f32x4 zv = {0.f,0.f,0.f,0.f};
        acc[mt][ct] = zv;
      }

#pragma unroll
    for (int kb = 0; kb < 4; ++kb){
      // layer 1 for this k-slice, 3-way bf16 trunc-split, A-frag order
      s16x8 A0[2], A1[2], A2[2];
#pragma unroll
      for (int u = 0; u < 8; ++u){
        const int k = kb*32 + lhi*8 + u;          // per-lane k
        const float4 t1 = ((const float4*)(sm+T1B))[k];
#pragma unroll
        for (int mt = 0; mt < 2; ++mt){
          const float pre = fmaf(prx[mt], t1.x,
                            fmaf(pry[mt], t1.y,
                            fmaf(prz[mt], t1.z, t1.w)));
          const float h = softplus_f(pre);
          unsigned short uh, um, ul;
          split3(h, uh, um, ul);
          A0[mt][u] = (short)uh; A1[mt][u] = (short)um; A2[mt][u] = (short)ul;
        }
      }
      // layer 2: 6-product bf16x3 MFMA (fp32-exact dot), all 8 col-tiles
#pragma unroll
      for (int ct = 0; ct < 8; ++ct){
        const s16x8 B0  = *(const s16x8*)(sm + WB(0,ct,kb) + lane*16);
        const s16x8 B1  = *(const s16x8*)(sm + WB(1,ct,kb) + lane*16);
        const s16x8 B2w = *(const s16x8*)(sm + WB(2,ct,kb) + lane*16);
#pragma unroll
        for (int mt = 0; mt < 2; ++mt){
          f32x4 a = acc[mt][ct];
          a = __builtin_amdgcn_mfma_f32_16x16x32_bf16(A0[mt], B0,  a, 0,0,0);
          a = __builtin_amdgcn_mfma_f32_16x16x32_bf16(A0[mt], B1,  a, 0,0,0);
          a = __builtin_amdgcn_mfma_f32_16x16x32_bf16(A1[mt], B0,  a, 0,0,0);
          a = __builtin_amdgcn_mfma_f32_16x16x32_bf16(A0[mt], B2w, a, 0,0,0);
          a = __builtin_amdgcn_mfma_f32_16x16x32_bf16(A1[mt], B1,  a, 0,0,0);
          a = __builtin_amdgcn_mfma_f32_16x16x32_bf16(A2[mt], B0,  a, 0,0,0);
          acc[mt][ct] = a;
        }
      }
    }

    // layer 3: sdf[row] = sum_col sp(C+b2)*W3 (+b3 added at read)
    float b2v[8], w3v[8];
#pragma unroll
    for (int ct = 0; ct < 8; ++ct){
      const int col = ct*16 + l15;
      b2v[ct] = ((const float*)(sm+B2B))[col];
      w3v[ct] = ((const float*)(sm+W3B))[col];
    }
#pragma unroll
    for (int mt = 0; mt < 2; ++mt){
#pragma unroll
      for (int i = 0; i < 4; ++i){
        // C layout (m89-verified): row = wave*32+mt*16+lhi*4+i, col = ct*16+l15
        float v = 0.f;
#pragma unroll
        for (int ct = 0; ct < 8; ++ct)
          v = fmaf(softplus_f(acc[mt][ct][i] + b2v[ct]), w3v[ct], v);
        v += __shfl_xor(v, 1);
        v += __shfl_xor(v, 2);
        v += __shfl_xor(v, 4);
        v += __shfl_xor(v, 8);                   // reduce over 16 col-lanes
        if (l15 == 0)
          ((float*)(sm+SDFB))[wave*32 + mt*16 + lhi*4 + i] = v;
      }
    }
  }
  __syncthreads();                               // SDFB ready
}

// Compact (per-wave LDS atomicAdd, rotating counter slot) + eval + gather.
// 2 barriers on the eval path, 1 when count==0. Row order is scheduler-
// dependent but per-channel values are position-independent -> deterministic.
__device__ __forceinline__ float do_eval(unsigned char* sm, int t, bool flag,
                                         float px, float py, float pz,
                                         float prev, int evalIdx){
  const int lane = t & 63;
  int* cnt = (int*)(sm + CNTB);
  const unsigned long long bal = __ballot(flag);
  const int pc = __popcll(bal);
  int base = 0;
  if (pc){                                       // wave-uniform condition
    int old = 0;
    if (lane == 0) old = atomicAdd(&cnt[evalIdx], pc);
    base = __shfl(old, 0);                       // all lanes execute
  }
  const int slot = base + __popcll(bal & ((1ULL << lane) - 1ULL));
  if (flag){
    ((float*)(sm+PXB))[slot] = px;
    ((float*)(sm+PYB))[slot] = py;
    ((float*)(sm+PZB))[slot] = pz;
  }
  __syncthreads();                               // points + counter visible
  const int total = cnt[evalIdx];                // uniform
  if (total == 0) return prev;                   // block-uniform
  eval_blockN(sm, t, (total + 31) >> 5);         // ends with barrier
  float r = prev;
  if (flag)
    r = ((const float*)(sm+SDFB))[slot] + *((const float*)(sm+B3B));
  return r;
}

__global__ __launch_bounds__(512, 2)
void trace_kernel(const float* __restrict__ rays_d, const float* __restrict__ rays_o,
                  const float* __restrict__ W1, const float* __restrict__ b1,
                  const float* __restrict__ W2, const float* __restrict__ b2,
                  const float* __restrict__ W3, const float* __restrict__ b3,
                  float* __restrict__ out)
{
  __shared__ __align__(16) unsigned char sm[LDSZ];
  const int t = threadIdx.x;

  // ---- per-channel identity + ray loads FIRST (latency hides under staging)
  const bool own = (t < 256);
  const int chan = blockIdx.x * 256 + (t & 255);
  const int ray  = chan >> 1;
  const int c01  = chan & 1;
  const float sgn = c01 ? -1.0f : 1.0f;

  float dx=0, dy=0, dz=0, ox=0, oy=0, oz=0;
  if (own){
    dx = rays_d[ray*3+0]; dy = rays_d[ray*3+1]; dz = rays_d[ray*3+2];
    ox = rays_o[ray*3+0]; oy = rays_o[ray*3+1]; oz = rays_o[ray*3+2];
  }

  // ---- stage W2: 3-split bf16, B-fragment order, conflict-free b128 writes.
  for (int si = t; si < 2048; si += 512){
    const int k    = si & 127;
    const int joct = si >> 7;
    s16x8 vh, vm, vl;
#pragma unroll
    for (int jj = 0; jj < 8; ++jj){
      const float w = W2[(joct*8 + jj)*128 + k];   // coalesced over lanes (k)
      unsigned short uh, um, ul;
      split3(w, uh, um, ul);
      vh[jj] = (short)uh; vm[jj] = (short)um; vl[jj] = (short)ul;
    }
    const int ct = k >> 4, kb = joct >> 2;
    const int slot = ((joct & 3)*16 + (k & 15))*16;
    *(s16x8*)(sm + WB(0,ct,kb) + slot) = vh;
    *(s16x8*)(sm + WB(1,ct,kb) + slot) = vm;
    *(s16x8*)(sm + WB(2,ct,kb) + slot) = vl;
  }
  if (t < 128){
    ((float4*)(sm+T1B))[t] = make_float4(W1[t], W1[128+t], W1[256+t], b1[t]);
    ((float*)(sm+B2B))[t] = b2[t];
    ((float*)(sm+W3B))[t] = W3[t];
  }
  if (t == 0) *((float*)(sm+B3B)) = b3[0];
  if (t < 32) ((int*)(sm+CNTB))[t] = 0;          // rotating counters, once

  // ---- origin eval: both channels share the SAME point (z=0) -> only even
  // channels evaluate; slots are STATIC (slot = t>>1), no ballot/atomic.
  // Both siblings read SDFB[t>>1] directly afterwards (no shfl needed).
  if (own && (c01 == 0)){
    const int slot = t >> 1;                     // 0..127
    ((float*)(sm+PXB))[slot] = ox;
    ((float*)(sm+PYB))[slot] = oy;
    ((float*)(sm+PZB))[slot] = oz;
  }
  __syncthreads();                               // staging + points visible
  eval_blockN(sm, t, 4);                         // 128 rows, ends w/ barrier
  float next_sdf = own
      ? ((const float*)(sm+SDFB))[(t & 255) >> 1] + *((const float*)(sm+B3B))
      : 0.f;

  float z = 0.f, sv = 0.f;
  float px = ox, py = oy, pz = oz;
  bool m = own;
  int evalIdx = 0;

  for (int it = 0; it < 6; ++it){
    sv = m ? next_sdf : 0.f;
    sv = (sv <= THRS) ? 0.f : sv;
    m = m && (sv > THRS);
    z = fmaf(sgn, sv, z);
    px = fmaf(z, dx, ox); py = fmaf(z, dy, oy); pz = fmaf(z, dz, oz);

    // step eval: only channels still marching
    next_sdf = do_eval(sm, t, m, px, py, pz, 0.f, evalIdx++);

    bool fm = own && (next_sdf < 0.f);
    float step = 0.5f;
    for (int fi = 0; fi < 3; ++fi){
      if (fm){
        z = fmaf(-step*sgn, sv, z);
        px = fmaf(z, dx, ox); py = fmaf(z, dy, oy); pz = fmaf(z, dz, oz);
      }
      // fix eval: only overshooting channels (compacted)
      next_sdf = do_eval(sm, t, fm, px, py, pz, next_sdf, evalIdx++);
      fm = own && (next_sdf < 0.f);
      step *= 0.5f;
    }

    // cross-channel coupling: adjacent thread holds the sibling channel
    const float zo = __shfl_xor(z, 1);             // unconditional
    const bool pair = c01 ? (zo < z) : (z < zo);
    m = m && pair;

    // all-dead fixed-point: remaining iterations are exact no-ops
    if (!__syncthreads_or((int)m)) break;
  }

  if (own){
    // final top-of-loop mask update
    sv = m ? next_sdf : 0.f;
    sv = (sv <= THRS) ? 0.f : sv;
    m = m && (sv > THRS);

    // outputs: points (2,N,3), z (2,N), mask (2,N) flat
    const size_t pb = (size_t)c01 * NRAYS * 3 + (size_t)ray * 3;
    out[pb+0] = px; out[pb+1] = py; out[pb+2] = pz;
    out[2*NRAYS*3 + (size_t)c01*NRAYS + ray] = z;
    out[2*NRAYS*3 + 2*NRAYS + (size_t)c01*NRAYS + ray] = m ? 1.f : 0.f;
  }
}

extern "C" void kernel_launch(void* const* d_in, const int* in_sizes, int n_in,
                              void* d_out, int out_size, void* d_ws, size_t ws_size,
                              hipStream_t stream) {
  const float* rays_d = (const float*)d_in[0];
  const float* rays_o = (const float*)d_in[1];
  const float* W1 = (const float*)d_in[2];
  const float* b1 = (const float*)d_in[3];
  const float* W2 = (const float*)d_in[4];
  const float* b2 = (const float*)d_in[5];
  const float* W3 = (const float*)d_in[6];
  const float* b3 = (const float*)d_in[7];
  float* out = (float*)d_out;
  (void)d_ws; (void)ws_size;

  // 256 blocks x 512 threads; each block owns 256 ray-channels (1 block/CU)
  trace_kernel<<<256, 512, 0, stream>>>(
      rays_d, rays_o, W1, b1, W2, b2, W3, b3, out);
}

// Round 12
// 24.938 us; speedup vs baseline: 11.9864x; 1.0129x over previous
//
#include <hip/hip_runtime.h>

#define NRAYS 32768
#define THRS  5e-5f

typedef float f32x4 __attribute__((ext_vector_type(4)));
typedef short s16x8 __attribute__((ext_vector_type(8)));

// ---- LDS byte map (105616 B total, 1 block/CU) ----
#define WB(s,ct,kb) ((((s)*8+(ct))*4+(kb))*1024)
#define T1B  98304   // float4[128] = (W1x,W1y,W1z,b1)
#define B2B  100352  // float[128]
#define W3B  100864  // float[128]
#define B3B  101376  // float (padded to 16)
#define PXB  101392  // float[256] compacted point x
#define PYB  102416
#define PZB  103440
#define SDFB 104464  // float[256]
#define CNTB 105488  // int[32] rotating compaction counters (zeroed once)
#define LDSZ 105616

// Cheap softplus: max(x,0) + ln2 * log2(1 + 2^(-|x|*log2e)).
__device__ __forceinline__ float softplus_f(float x){
  const float L2E = 1.44269504088896340f;
  const float LN2 = 0.69314718055994531f;
  float y = __builtin_amdgcn_exp2f(-fabsf(x) * L2E);
  float l = __builtin_amdgcn_logf(1.0f + y);      // log2(1+y)
  return fmaf(LN2, l, fmaxf(x, 0.0f));
}

__device__ __forceinline__ float bf16tof(unsigned short h){
  return __uint_as_float(((unsigned int)h) << 16);
}
// Truncation 3-way bf16 split: exact for fp32 (3x8 = 24 mantissa bits).
__device__ __forceinline__ void split3(float h, unsigned short& a0,
                                       unsigned short& a1, unsigned short& a2){
  a0 = (unsigned short)(__float_as_uint(h) >> 16);
  const float r1 = h - bf16tof(a0);
  a1 = (unsigned short)(__float_as_uint(r1) >> 16);
  const float r2 = r1 - bf16tof(a1);
  a2 = (unsigned short)(__float_as_uint(r2) >> 16);
}

// Batched MLP eval over compacted rows 0..nw*32-1. Waves >= nw skip all
// work (B-read traffic scales with nw). Ends with a barrier (SDFB ready).
__device__ __forceinline__ void eval_blockN(unsigned char* sm, int t, int nw){
  const int lane = t & 63;
  const int wave = t >> 6;          // 0..7
  const int l15  = lane & 15;
  const int lhi  = lane >> 4;

  if (wave < nw){
    float prx[2], pry[2], prz[2];
#pragma unroll
    for (int mt = 0; mt < 2; ++mt){
      const int row = wave*32 + mt*16 + l15;
      prx[mt] = ((const float*)(sm+PXB))[row];
      pry[mt] = ((const float*)(sm+PYB))[row];
      prz[mt] = ((const float*)(sm+PZB))[row];
    }

    f32x4 acc[2][8];
#pragma unroll
    for (int mt = 0; mt < 2; ++mt)
#pragma unroll
      for (int ct = 0; ct < 8; ++ct){
        f32x4 zv = {0.f,0.f,0.f,0.f};
        acc[mt][ct] = zv;
      }

#pragma unroll
    for (int kb = 0; kb < 4; ++kb){
      s16x8 A0[2], A1[2], A2[2];
#pragma unroll
      for (int u = 0; u < 8; ++u){
        const int k = kb*32 + lhi*8 + u;          // per-lane k
        const float4 t1 = ((const float4*)(sm+T1B))[k];
#pragma unroll
        for (int mt = 0; mt < 2; ++mt){
          const float pre = fmaf(prx[mt], t1.x,
                            fmaf(pry[mt], t1.y,
                            fmaf(prz[mt], t1.z, t1.w)));
          const float h = softplus_f(pre);
          unsigned short uh, um, ul;
          split3(h, uh, um, ul);
          A0[mt][u] = (short)uh; A1[mt][u] = (short)um; A2[mt][u] = (short)ul;
        }
      }
#pragma unroll
      for (int ct = 0; ct < 8; ++ct){
        const s16x8 B0  = *(const s16x8*)(sm + WB(0,ct,kb) + lane*16);
        const s16x8 B1  = *(const s16x8*)(sm + WB(1,ct,kb) + lane*16);
        const s16x8 B2w = *(const s16x8*)(sm + WB(2,ct,kb) + lane*16);
#pragma unroll
        for (int mt = 0; mt < 2; ++mt){
          f32x4 a = acc[mt][ct];
          a = __builtin_amdgcn_mfma_f32_16x16x32_bf16(A0[mt], B0,  a, 0,0,0);
          a = __builtin_amdgcn_mfma_f32_16x16x32_bf16(A0[mt], B1,  a, 0,0,0);
          a = __builtin_amdgcn_mfma_f32_16x16x32_bf16(A1[mt], B0,  a, 0,0,0);
          a = __builtin_amdgcn_mfma_f32_16x16x32_bf16(A0[mt], B2w, a, 0,0,0);
          a = __builtin_amdgcn_mfma_f32_16x16x32_bf16(A1[mt], B1,  a, 0,0,0);
          a = __builtin_amdgcn_mfma_f32_16x16x32_bf16(A2[mt], B0,  a, 0,0,0);
          acc[mt][ct] = a;
        }
      }
    }

    float b2v[8], w3v[8];
#pragma unroll
    for (int ct = 0; ct < 8; ++ct){
      const int col = ct*16 + l15;
      b2v[ct] = ((const float*)(sm+B2B))[col];
      w3v[ct] = ((const float*)(sm+W3B))[col];
    }
#pragma unroll
    for (int mt = 0; mt < 2; ++mt){
#pragma unroll
      for (int i = 0; i < 4; ++i){
        // C layout (m89-verified): row = wave*32+mt*16+lhi*4+i, col = ct*16+l15
        float v = 0.f;
#pragma unroll
        for (int ct = 0; ct < 8; ++ct)
          v = fmaf(softplus_f(acc[mt][ct][i] + b2v[ct]), w3v[ct], v);
        v += __shfl_xor(v, 1);
        v += __shfl_xor(v, 2);
        v += __shfl_xor(v, 4);
        v += __shfl_xor(v, 8);                   // reduce over 16 col-lanes
        if (l15 == 0)
          ((float*)(sm+SDFB))[wave*32 + mt*16 + lhi*4 + i] = v;
      }
    }
  }
  __syncthreads();                               // SDFB ready
}

// Compact (per-wave LDS atomicAdd, rotating counter slot) + eval + gather.
__device__ __forceinline__ float do_eval(unsigned char* sm, int t, bool flag,
                                         float px, float py, float pz,
                                         float prev, int evalIdx){
  const int lane = t & 63;
  int* cnt = (int*)(sm + CNTB);
  const unsigned long long bal = __ballot(flag);
  const int pc = __popcll(bal);
  int base = 0;
  if (pc){                                       // wave-uniform condition
    int old = 0;
    if (lane == 0) old = atomicAdd(&cnt[evalIdx], pc);
    base = __shfl(old, 0);                       // all lanes execute
  }
  const int slot = base + __popcll(bal & ((1ULL << lane) - 1ULL));
  if (flag){
    ((float*)(sm+PXB))[slot] = px;
    ((float*)(sm+PYB))[slot] = py;
    ((float*)(sm+PZB))[slot] = pz;
  }
  __syncthreads();                               // points + counter visible
  const int total = cnt[evalIdx];                // uniform
  if (total == 0) return prev;                   // block-uniform
  eval_blockN(sm, t, (total + 31) >> 5);         // ends with barrier
  float r = prev;
  if (flag)
    r = ((const float*)(sm+SDFB))[slot] + *((const float*)(sm+B3B));
  return r;
}

// Speculative 3-probe eval (fix-overshoot chain is oblivious: probe points
// depend only on (z, sv), not on intermediate results). 3 rows per flagged
// channel, interleaved. usedSpec=false => caller must run sequential path.
__device__ __forceinline__ void do_eval3(unsigned char* sm, int t, bool flag,
    float p1x, float p1y, float p1z,
    float p2x, float p2y, float p2z,
    float p3x, float p3y, float p3z,
    int evalIdx, float& e1, float& e2, float& e3, bool& usedSpec){
  const int lane = t & 63;
  int* cnt = (int*)(sm + CNTB);
  const unsigned long long bal = __ballot(flag);
  const int pc = __popcll(bal);
  int base = 0;
  if (pc){
    int old = 0;
    if (lane == 0) old = atomicAdd(&cnt[evalIdx], pc);
    base = __shfl(old, 0);
  }
  const int r = base + __popcll(bal & ((1ULL << lane) - 1ULL));
  if (flag && 3*r + 2 < 256){                    // guard vs overflow
    float* PX = (float*)(sm+PXB);
    float* PY = (float*)(sm+PYB);
    float* PZ = (float*)(sm+PZB);
    PX[3*r+0] = p1x; PY[3*r+0] = p1y; PZ[3*r+0] = p1z;
    PX[3*r+1] = p2x; PY[3*r+1] = p2y; PZ[3*r+1] = p2z;
    PX[3*r+2] = p3x; PY[3*r+2] = p3y; PZ[3*r+2] = p3z;
  }
  __syncthreads();                               // points + counter visible
  const int total = cnt[evalIdx] * 3;            // uniform
  e1 = 0.f; e2 = 0.f; e3 = 0.f;
  if (total == 0){ usedSpec = true; return; }    // no overshoot anywhere
  if (total > 256){ usedSpec = false; return; }  // rare: sequential fallback
  eval_blockN(sm, t, (total + 31) >> 5);
  usedSpec = true;
  if (flag){
    const float b3v = *((const float*)(sm+B3B));
    const float* S = (const float*)(sm+SDFB);
    e1 = S[3*r+0] + b3v;
    e2 = S[3*r+1] + b3v;
    e3 = S[3*r+2] + b3v;
  }
}

__global__ __launch_bounds__(512, 2)
void trace_kernel(const float* __restrict__ rays_d, const float* __restrict__ rays_o,
                  const float* __restrict__ W1, const float* __restrict__ b1,
                  const float* __restrict__ W2, const float* __restrict__ b2,
                  const float* __restrict__ W3, const float* __restrict__ b3,
                  float* __restrict__ out)
{
  __shared__ __align__(16) unsigned char sm[LDSZ];
  const int t = threadIdx.x;

  // ---- ray loads first (global latency hides under W2 staging VALU)
  const bool own = (t < 256);
  const int chan = blockIdx.x * 256 + (t & 255);
  const int ray  = chan >> 1;
  const int c01  = chan & 1;
  const float sgn = c01 ? -1.0f : 1.0f;

  float dx=0, dy=0, dz=0, ox=0, oy=0, oz=0;
  if (own){
    dx = rays_d[ray*3+0]; dy = rays_d[ray*3+1]; dz = rays_d[ray*3+2];
    ox = rays_o[ray*3+0]; oy = rays_o[ray*3+1]; oz = rays_o[ray*3+2];
  }

  // ---- stage W2: 3-split bf16, B-fragment order, conflict-free b128 writes.
  for (int si = t; si < 2048; si += 512){
    const int k    = si & 127;
    const int joct = si >> 7;
    s16x8 vh, vm, vl;
#pragma unroll
    for (int jj = 0; jj < 8; ++jj){
      const float w = W2[(joct*8 + jj)*128 + k];   // coalesced over lanes (k)
      unsigned short uh, um, ul;
      split3(w, uh, um, ul);
      vh[jj] = (short)uh; vm[jj] = (short)um; vl[jj] = (short)ul;
    }
    const int ct = k >> 4, kb = joct >> 2;
    const int slot = ((joct & 3)*16 + (k & 15))*16;
    *(s16x8*)(sm + WB(0,ct,kb) + slot) = vh;
    *(s16x8*)(sm + WB(1,ct,kb) + slot) = vm;
    *(s16x8*)(sm + WB(2,ct,kb) + slot) = vl;
  }
  if (t < 128){
    ((float4*)(sm+T1B))[t] = make_float4(W1[t], W1[128+t], W1[256+t], b1[t]);
    ((float*)(sm+B2B))[t] = b2[t];
    ((float*)(sm+W3B))[t] = W3[t];
  }
  if (t == 0) *((float*)(sm+B3B)) = b3[0];
  if (t < 32) ((int*)(sm+CNTB))[t] = 0;          // rotating counters, once

  // ---- origin eval: channels of a ray share the SAME point (z=0) -> only
  // even channels evaluate; STATIC slots (t>>1); both siblings read directly.
  if (own && (c01 == 0)){
    const int slot = t >> 1;                     // 0..127
    ((float*)(sm+PXB))[slot] = ox;
    ((float*)(sm+PYB))[slot] = oy;
    ((float*)(sm+PZB))[slot] = oz;
  }
  __syncthreads();                               // staging + points visible
  eval_blockN(sm, t, 4);                         // 128 rows, ends w/ barrier
  float next_sdf = own
      ? ((const float*)(sm+SDFB))[(t & 255) >> 1] + *((const float*)(sm+B3B))
      : 0.f;

  float z = 0.f, sv = 0.f;
  float px = ox, py = oy, pz = oz;
  bool m = own;
  int evalIdx = 0;

  for (int it = 0; it < 6; ++it){
    sv = m ? next_sdf : 0.f;
    sv = (sv <= THRS) ? 0.f : sv;
    m = m && (sv > THRS);
    z = fmaf(sgn, sv, z);
    px = fmaf(z, dx, ox); py = fmaf(z, dy, oy); pz = fmaf(z, dz, oz);

    // step eval: only channels still marching
    next_sdf = do_eval(sm, t, m, px, py, pz, 0.f, evalIdx);

    bool fm = own && (next_sdf < 0.f);

    // ---- speculative fix: probe chain is oblivious; same fmaf chain as
    // the sequential path -> bitwise-identical z values.
    const float z1p = fmaf(-0.5f  * sgn, sv, z);
    const float z2p = fmaf(-0.25f * sgn, sv, z1p);
    const float z3p = fmaf(-0.125f* sgn, sv, z2p);
    float e1, e2, e3; bool usedSpec;
    do_eval3(sm, t, fm,
             fmaf(z1p,dx,ox), fmaf(z1p,dy,oy), fmaf(z1p,dz,oz),
             fmaf(z2p,dx,ox), fmaf(z2p,dy,oy), fmaf(z2p,dz,oz),
             fmaf(z3p,dx,ox), fmaf(z3p,dy,oy), fmaf(z3p,dz,oz),
             evalIdx + 1, e1, e2, e3, usedSpec);
    if (usedSpec){
      if (fm){
        if (e1 >= 0.f)      { z = z1p; next_sdf = e1; }
        else if (e2 >= 0.f) { z = z2p; next_sdf = e2; }
        else                { z = z3p; next_sdf = e3; }
        px = fmaf(z, dx, ox); py = fmaf(z, dy, oy); pz = fmaf(z, dz, oz);
      }
    } else {
      // sequential fallback (rare; bitwise-identical semantics)
      float step = 0.5f;
      for (int fi = 0; fi < 3; ++fi){
        if (fm){
          z = fmaf(-step*sgn, sv, z);
          px = fmaf(z, dx, ox); py = fmaf(z, dy, oy); pz = fmaf(z, dz, oz);
        }
        next_sdf = do_eval(sm, t, fm, px, py, pz, next_sdf, evalIdx + 2 + fi);
        fm = own && (next_sdf < 0.f);
        step *= 0.5f;
      }
    }
    evalIdx += 5;

    // cross-channel coupling: adjacent thread holds the sibling channel
    const float zo = __shfl_xor(z, 1);             // unconditional
    const bool pair = c01 ? (zo < z) : (z < zo);
    m = m && pair;

    // all-dead fixed-point: remaining iterations are exact no-ops
    if (!__syncthreads_or((int)m)) break;
  }

  if (own){
    // final top-of-loop mask update
    sv = m ? next_sdf : 0.f;
    sv = (sv <= THRS) ? 0.f : sv;
    m = m && (sv > THRS);

    // outputs: points (2,N,3), z (2,N), mask (2,N) flat
    const size_t pb = (size_t)c01 * NRAYS * 3 + (size_t)ray * 3;
    out[pb+0] = px; out[pb+1] = py; out[pb+2] = pz;
    out[2*NRAYS*3 + (size_t)c01*NRAYS + ray] = z;
    out[2*NRAYS*3 + 2*NRAYS + (size_t)c01*NRAYS + ray] = m ? 1.f : 0.f;
  }
}

extern "C" void kernel_launch(void* const* d_in, const int* in_sizes, int n_in,
                              void* d_out, int out_size, void* d_ws, size_t ws_size,
                              hipStream_t stream) {
  const float* rays_d = (const float*)d_in[0];
  const float* rays_o = (const float*)d_in[1];
  const float* W1 = (const float*)d_in[2];
  const float* b1 = (const float*)d_in[3];
  const float* W2 = (const float*)d_in[4];
  const float* b2 = (const float*)d_in[5];
  const float* W3 = (const float*)d_in[6];
  const float* b3 = (const float*)d_in[7];
  float* out = (float*)d_out;
  (void)d_ws; (void)ws_size;

  // 256 blocks x 512 threads; each block owns 256 ray-channels (1 block/CU)
  trace_kernel<<<256, 512, 0, stream>>>(
      rays_d, rays_o, W1, b1, W2, b2, W3, b3, out);
}